// Round 1
// baseline (1989.713 us; speedup 1.0000x reference)
//
#include <hip/hip_runtime.h>

static constexpr int NW = 20000, NT = 2000, ND = 5000;
static constexpr int E_WW = 150000, E_WT = 80000, E_WD = 80000, E_TT = 20000, E_TD = 40000;

// ---------------- f32 tiled GEMM: C[M,256] = A[M,256] @ W[256,256] + bias ----------------
__global__ __launch_bounds__(256) void gemm_bias256(
    const float* __restrict__ A, const float* __restrict__ W,
    const float* __restrict__ bias, float* __restrict__ C, int M)
{
  __shared__ float As[16][68];   // [k][m], padded
  __shared__ float Bs[16][68];   // [k][n], padded (68*4=272B, 16B-aligned rows)
  const int bm = blockIdx.x * 64;
  const int bn = blockIdx.y * 64;
  const int tid = threadIdx.x;
  const int tx = tid & 15, ty = tid >> 4;
  const int ar = tid >> 2;            // 0..63 (A tile row)
  const int ac = (tid & 3) * 4;       // 0,4,8,12 (A tile k)
  const int br = tid >> 4;            // 0..15 (B tile k)
  const int bc = (tid & 15) * 4;      // 0..60 (B tile n)
  const int arow = bm + ar;
  const bool aval = arow < M;
  float acc[4][4] = {};
  for (int k0 = 0; k0 < 256; k0 += 16) {
    float4 av = make_float4(0.f, 0.f, 0.f, 0.f);
    if (aval) av = *(const float4*)(A + (size_t)arow * 256 + k0 + ac);
    float4 bv = *(const float4*)(W + (size_t)(k0 + br) * 256 + bn + bc);
    __syncthreads();
    As[ac + 0][ar] = av.x; As[ac + 1][ar] = av.y; As[ac + 2][ar] = av.z; As[ac + 3][ar] = av.w;
    *(float4*)&Bs[br][bc] = bv;
    __syncthreads();
#pragma unroll
    for (int kk = 0; kk < 16; kk++) {
      float4 a4 = *(const float4*)&As[kk][ty * 4];
      float4 b4 = *(const float4*)&Bs[kk][tx * 4];
      float a0[4] = {a4.x, a4.y, a4.z, a4.w};
      float b0[4] = {b4.x, b4.y, b4.z, b4.w};
#pragma unroll
      for (int i = 0; i < 4; i++)
#pragma unroll
        for (int j = 0; j < 4; j++) acc[i][j] += a0[i] * b0[j];
    }
  }
  float4 bsv = *(const float4*)(bias + bn + tx * 4);
#pragma unroll
  for (int i = 0; i < 4; i++) {
    int row = bm + ty * 4 + i;
    if (row < M) {
      float4 o = make_float4(acc[i][0] + bsv.x, acc[i][1] + bsv.y,
                             acc[i][2] + bsv.z, acc[i][3] + bsv.w);
      *(float4*)(C + (size_t)row * 256 + bn + tx * 4) = o;
    }
  }
}

// ---------------- per-node per-head 32x32 transform: out[n,h,k] = sum_d in[n,h,d]*w[h,d,k] ----
__global__ __launch_bounds__(256) void head_transform(
    const float* __restrict__ in, const float* __restrict__ w,
    float* __restrict__ out, int N)
{
  __shared__ float wsm[8192];  // 8 heads * 32*32
  __shared__ float xs[256];
  for (int i = threadIdx.x; i < 8192; i += 256) wsm[i] = w[i];
  const int h = threadIdx.x >> 5;
  const int k = threadIdx.x & 31;
  const int n0 = blockIdx.x * 16;
  for (int nn = 0; nn < 16; nn++) {
    int n = n0 + nn;
    if (n >= N) break;
    __syncthreads();
    xs[threadIdx.x] = in[(size_t)n * 256 + threadIdx.x];
    __syncthreads();
    float acc = 0.f;
#pragma unroll
    for (int d = 0; d < 32; d++) acc += xs[h * 32 + d] * wsm[h * 1024 + d * 32 + k];
    out[(size_t)n * 256 + threadIdx.x] = acc;
  }
}

__global__ void fill_neginf(float* __restrict__ p, int n) {
  int i = blockIdx.x * blockDim.x + threadIdx.x;
  if (i < n) p[i] = __int_as_float(0xff800000);  // -inf
}

__device__ __forceinline__ void atomicMaxFloat(float* addr, float v) {
  if (v >= 0.f) atomicMax((int*)addr, __float_as_int(v));
  else          atomicMin((unsigned int*)addr, __float_as_uint(v));
}

// ---------------- edge attention logit + segment max ----------------
__global__ __launch_bounds__(256) void edge_att(
    const float* __restrict__ q, const float* __restrict__ khat,
    const int* __restrict__ src, const int* __restrict__ dst,
    const float* __restrict__ pri, float* __restrict__ att,
    float* __restrict__ m, int E)
{
  int t = blockIdx.x * blockDim.x + threadIdx.x;
  if (t >= E * 8) return;
  int e = t >> 3, h = t & 7;
  int sN = src[e], dN = dst[e];
  const float4* qp = (const float4*)(q + (size_t)dN * 256 + h * 32);
  const float4* kp = (const float4*)(khat + (size_t)sN * 256 + h * 32);
  float acc = 0.f;
#pragma unroll
  for (int i = 0; i < 8; i++) {
    float4 a = qp[i], b = kp[i];
    acc += a.x * b.x + a.y * b.y + a.z * b.z + a.w * b.w;
  }
  float v = acc * pri[h] * 0.17677669529663687f;  // 1/sqrt(32)
  att[t] = v;
  atomicMaxFloat(m + (size_t)dN * 8 + h, v);
}

// ---------------- exp(att - m) + segment sum ----------------
__global__ __launch_bounds__(256) void edge_exp(
    float* __restrict__ att, const int* __restrict__ dst,
    const float* __restrict__ m, float* __restrict__ s, int E)
{
  int t = blockIdx.x * blockDim.x + threadIdx.x;
  if (t >= E * 8) return;
  int e = t >> 3, h = t & 7;
  int dN = dst[e];
  float ev = expf(att[t] - m[(size_t)dN * 8 + h]);
  att[t] = ev;
  atomicAdd(s + (size_t)dN * 8 + h, ev);
}

// ---------------- alpha * vhat scatter-add ----------------
__global__ __launch_bounds__(256) void edge_agg(
    const float* __restrict__ att, const float* __restrict__ s,
    const float* __restrict__ vhat, const int* __restrict__ src,
    const int* __restrict__ dst, float* __restrict__ agg, int E)
{
  int t = blockIdx.x * blockDim.x + threadIdx.x;
  int e = t >> 6, l = t & 63;
  if (e >= E) return;
  int sN = src[e], dN = dst[e];
  int h = l >> 3;
  float coef = att[(size_t)e * 8 + h] / fmaxf(s[(size_t)dN * 8 + h], 1e-9f);
  float4 v = *(const float4*)(vhat + (size_t)sN * 256 + l * 4);
  float* o = agg + (size_t)dN * 256 + l * 4;
  atomicAdd(o + 0, coef * v.x);
  atomicAdd(o + 1, coef * v.y);
  atomicAdd(o + 2, coef * v.z);
  atomicAdd(o + 3, coef * v.w);
}

// ---------------- relu + optional second etype + mean scale ----------------
__global__ void relu_mean(const float* __restrict__ a, const float* __restrict__ b,
                          float* __restrict__ out, float scale, int n)
{
  int i = blockIdx.x * blockDim.x + threadIdx.x;
  if (i >= n) return;
  float v = fmaxf(a[i], 0.f);
  if (b) v += fmaxf(b[i], 0.f);
  out[i] = v * scale;
}

// ---------------- skip-blend + LayerNorm (one block = one row of 256) ----------------
__global__ __launch_bounds__(256) void skip_ln(
    const float* __restrict__ trans, const float* __restrict__ feat,
    const float* __restrict__ skip, int skipIdx,
    const float* __restrict__ gamma, const float* __restrict__ beta,
    float* __restrict__ out)
{
  int row = blockIdx.x;
  int tid = threadIdx.x;
  float a = 1.f / (1.f + expf(-skip[skipIdx]));
  size_t idx = (size_t)row * 256 + tid;
  float x = trans[idx] * a + feat[idx] * (1.f - a);
  __shared__ float red[4];
  int lane = tid & 63, wid = tid >> 6;
  float sum = x;
#pragma unroll
  for (int o = 32; o > 0; o >>= 1) sum += __shfl_down(sum, o, 64);
  if (lane == 0) red[wid] = sum;
  __syncthreads();
  float mu = (red[0] + red[1] + red[2] + red[3]) * (1.f / 256.f);
  float d = x - mu;
  float vs = d * d;
#pragma unroll
  for (int o = 32; o > 0; o >>= 1) vs += __shfl_down(vs, o, 64);
  __syncthreads();
  if (lane == 0) red[wid] = vs;
  __syncthreads();
  float var = (red[0] + red[1] + red[2] + red[3]) * (1.f / 256.f);
  out[idx] = d * rsqrtf(var + 1e-5f) * gamma[tid] + beta[tid];
}

extern "C" void kernel_launch(void* const* d_in, const int* in_sizes, int n_in,
                              void* d_out, int out_size, void* d_ws, size_t ws_size,
                              hipStream_t stream) {
  const float* feat_w = (const float*)d_in[0];
  const float* feat_t = (const float*)d_in[1];
  const float* feat_d = (const float*)d_in[2];
  const float* Wk = (const float*)d_in[3];
  const float* bk = (const float*)d_in[4];
  const float* Wq = (const float*)d_in[5];
  const float* bq = (const float*)d_in[6];
  const float* Wv = (const float*)d_in[7];
  const float* bv = (const float*)d_in[8];
  const float* Wa = (const float*)d_in[9];
  const float* ba = (const float*)d_in[10];
  const float* ln_scale = (const float*)d_in[11];
  const float* ln_bias = (const float*)d_in[12];
  const float* skip = (const float*)d_in[13];
  const float* rel_pri = (const float*)d_in[14];
  const float* rel_att = (const float*)d_in[15];
  const float* rel_msg = (const float*)d_in[16];
  const int* src_ww = (const int*)d_in[17];
  const int* dst_ww = (const int*)d_in[18];
  const int* src_wt = (const int*)d_in[19];
  const int* dst_wt = (const int*)d_in[20];
  const int* src_wd = (const int*)d_in[21];
  const int* dst_wd = (const int*)d_in[22];
  const int* src_tt = (const int*)d_in[23];
  const int* dst_tt = (const int*)d_in[24];
  const int* src_td = (const int*)d_in[25];
  const int* dst_td = (const int*)d_in[26];
  float* out = (float*)d_out;
  float* ws = (float*)d_ws;

  // workspace layout (floats)
  float* q_w    = ws;                  // 5,120,000
  float* q_t    = q_w + 5120000;       //   512,000
  float* q_d    = q_t + 512000;        // 1,280,000
  float* kbuf   = q_d + 1280000;       // 5,120,000 (k of current src ntype)
  float* vbuf   = kbuf + 5120000;      // 5,120,000
  float* khat   = vbuf + 5120000;      // 5,120,000
  float* vhat   = khat + 5120000;      // 5,120,000
  float* agg_ww = vhat + 5120000;      // 5,120,000
  float* agg_wt = agg_ww + 5120000;    //   512,000
  float* agg_wd = agg_wt + 512000;     // 1,280,000
  float* agg_tt = agg_wd + 1280000;    //   512,000
  float* agg_td = agg_tt + 512000;     // 1,280,000
  float* attb   = agg_td + 1280000;    // 1,200,000 (max E*8)
  float* mbuf   = attb + 1200000;      //   160,000
  float* sbuf   = mbuf + 160000;       //   160,000

  // zero all aggregation buffers (contiguous region, 8,704,000 floats)
  hipMemsetAsync(agg_ww, 0, (size_t)8704000 * 4, stream);

  dim3 b256(256);
  auto cdiv = [](int a, int b) { return (a + b - 1) / b; };

  // projections
  gemm_bias256<<<dim3(cdiv(NW, 64), 4), b256, 0, stream>>>(feat_w, Wq, bq, q_w, NW);
  gemm_bias256<<<dim3(cdiv(NT, 64), 4), b256, 0, stream>>>(feat_t, Wq + 65536, bq + 256, q_t, NT);
  gemm_bias256<<<dim3(cdiv(ND, 64), 4), b256, 0, stream>>>(feat_d, Wq + 2 * 65536, bq + 512, q_d, ND);
  gemm_bias256<<<dim3(cdiv(NW, 64), 4), b256, 0, stream>>>(feat_w, Wk, bk, kbuf, NW);
  gemm_bias256<<<dim3(cdiv(NW, 64), 4), b256, 0, stream>>>(feat_w, Wv, bv, vbuf, NW);

  auto do_rel = [&](int r, int Nsrc, int Ndst, const int* srcI, const int* dstI, int E,
                    const float* qbuf, float* agg) {
    head_transform<<<cdiv(Nsrc, 16), b256, 0, stream>>>(kbuf, rel_att + (size_t)r * 8192, khat, Nsrc);
    head_transform<<<cdiv(Nsrc, 16), b256, 0, stream>>>(vbuf, rel_msg + (size_t)r * 8192, vhat, Nsrc);
    fill_neginf<<<cdiv(Ndst * 8, 256), b256, 0, stream>>>(mbuf, Ndst * 8);
    hipMemsetAsync(sbuf, 0, (size_t)Ndst * 8 * 4, stream);
    edge_att<<<cdiv(E * 8, 256), b256, 0, stream>>>(qbuf, khat, srcI, dstI, rel_pri + r * 8, attb, mbuf, E);
    edge_exp<<<cdiv(E * 8, 256), b256, 0, stream>>>(attb, dstI, mbuf, sbuf, E);
    edge_agg<<<cdiv(E * 64, 256), b256, 0, stream>>>(attb, sbuf, vhat, srcI, dstI, agg, E);
  };

  // word-source relations
  do_rel(0, NW, NW, src_ww, dst_ww, E_WW, q_w, agg_ww);
  do_rel(1, NW, NT, src_wt, dst_wt, E_WT, q_t, agg_wt);
  do_rel(2, NW, ND, src_wd, dst_wd, E_WD, q_d, agg_wd);
  // topic-source relations
  gemm_bias256<<<dim3(cdiv(NT, 64), 4), b256, 0, stream>>>(feat_t, Wk + 65536, bk + 256, kbuf, NT);
  gemm_bias256<<<dim3(cdiv(NT, 64), 4), b256, 0, stream>>>(feat_t, Wv + 65536, bv + 256, vbuf, NT);
  do_rel(3, NT, NT, src_tt, dst_tt, E_TT, q_t, agg_tt);
  do_rel(4, NT, ND, src_td, dst_td, E_TD, q_d, agg_td);

  // relu + cross-etype mean (reuse khat/vhat as t buffers)
  float* t_word  = khat;
  float* t_topic = vhat;
  float* t_doc   = vhat + 512000;
  relu_mean<<<cdiv(NW * 256, 256), b256, 0, stream>>>(agg_ww, (const float*)nullptr, t_word, 1.0f, NW * 256);
  relu_mean<<<cdiv(NT * 256, 256), b256, 0, stream>>>(agg_wt, agg_tt, t_topic, 0.5f, NT * 256);
  relu_mean<<<cdiv(ND * 256, 256), b256, 0, stream>>>(agg_wd, agg_td, t_doc, 0.5f, ND * 256);

  // output transform (reuse kbuf/vbuf as trans buffers)
  float* tr_w = kbuf;
  float* tr_t = vbuf;
  float* tr_d = vbuf + 512000;
  gemm_bias256<<<dim3(cdiv(NW, 64), 4), b256, 0, stream>>>(t_word, Wa, ba, tr_w, NW);
  gemm_bias256<<<dim3(cdiv(NT, 64), 4), b256, 0, stream>>>(t_topic, Wa + 65536, ba + 256, tr_t, NT);
  gemm_bias256<<<dim3(cdiv(ND, 64), 4), b256, 0, stream>>>(t_doc, Wa + 2 * 65536, ba + 512, tr_d, ND);

  // skip-blend + LayerNorm -> d_out (word, topic, doc concatenated)
  skip_ln<<<NW, b256, 0, stream>>>(tr_w, feat_w, skip, 0, ln_scale, ln_bias, out);
  skip_ln<<<NT, b256, 0, stream>>>(tr_t, feat_t, skip, 1, ln_scale + 256, ln_bias + 256, out + (size_t)NW * 256);
  skip_ln<<<ND, b256, 0, stream>>>(tr_d, feat_d, skip, 2, ln_scale + 512, ln_bias + 512, out + (size_t)(NW + NT) * 256);

  (void)in_sizes; (void)n_in; (void)out_size; (void)ws_size;
}

// Round 2
// 1023.385 us; speedup vs baseline: 1.9442x; 1.9442x over previous
//
#include <hip/hip_runtime.h>

static constexpr int NW = 20000, NT = 2000, ND = 5000;
static constexpr int E_WW = 150000, E_WT = 80000, E_WD = 80000, E_TT = 20000, E_TD = 40000;

// ---------------- f32 tiled GEMM: C[M,256] = A[M,256] @ W[256,256] + bias ----------------
__global__ __launch_bounds__(256) void gemm_bias256(
    const float* __restrict__ A, const float* __restrict__ W,
    const float* __restrict__ bias, float* __restrict__ C, int M)
{
  __shared__ float As[16][68];   // [k][m], padded
  __shared__ float Bs[16][68];   // [k][n], padded
  const int bm = blockIdx.x * 64;
  const int bn = blockIdx.y * 64;
  const int tid = threadIdx.x;
  const int tx = tid & 15, ty = tid >> 4;
  const int ar = tid >> 2;            // 0..63 (A tile row)
  const int ac = (tid & 3) * 4;       // 0,4,8,12 (A tile k)
  const int br = tid >> 4;            // 0..15 (B tile k)
  const int bc = (tid & 15) * 4;      // 0..60 (B tile n)
  const int arow = bm + ar;
  const bool aval = arow < M;
  float acc[4][4] = {};
  for (int k0 = 0; k0 < 256; k0 += 16) {
    float4 av = make_float4(0.f, 0.f, 0.f, 0.f);
    if (aval) av = *(const float4*)(A + (size_t)arow * 256 + k0 + ac);
    float4 bv = *(const float4*)(W + (size_t)(k0 + br) * 256 + bn + bc);
    __syncthreads();
    As[ac + 0][ar] = av.x; As[ac + 1][ar] = av.y; As[ac + 2][ar] = av.z; As[ac + 3][ar] = av.w;
    *(float4*)&Bs[br][bc] = bv;
    __syncthreads();
#pragma unroll
    for (int kk = 0; kk < 16; kk++) {
      float4 a4 = *(const float4*)&As[kk][ty * 4];
      float4 b4 = *(const float4*)&Bs[kk][tx * 4];
      float a0[4] = {a4.x, a4.y, a4.z, a4.w};
      float b0[4] = {b4.x, b4.y, b4.z, b4.w};
#pragma unroll
      for (int i = 0; i < 4; i++)
#pragma unroll
        for (int j = 0; j < 4; j++) acc[i][j] += a0[i] * b0[j];
    }
  }
  float4 bsv = *(const float4*)(bias + bn + tx * 4);
#pragma unroll
  for (int i = 0; i < 4; i++) {
    int row = bm + ty * 4 + i;
    if (row < M) {
      float4 o = make_float4(acc[i][0] + bsv.x, acc[i][1] + bsv.y,
                             acc[i][2] + bsv.z, acc[i][3] + bsv.w);
      *(float4*)(C + (size_t)row * 256 + bn + tx * 4) = o;
    }
  }
}

// ---------------- per-node per-head 32x32 transform ----------------
__global__ __launch_bounds__(256) void head_transform(
    const float* __restrict__ in, const float* __restrict__ w,
    float* __restrict__ out, int N)
{
  __shared__ float wsm[8192];  // 8 heads * 32*32
  __shared__ float xs[256];
  for (int i = threadIdx.x; i < 8192; i += 256) wsm[i] = w[i];
  const int h = threadIdx.x >> 5;
  const int k = threadIdx.x & 31;
  const int n0 = blockIdx.x * 16;
  for (int nn = 0; nn < 16; nn++) {
    int n = n0 + nn;
    if (n >= N) break;
    __syncthreads();
    xs[threadIdx.x] = in[(size_t)n * 256 + threadIdx.x];
    __syncthreads();
    float acc = 0.f;
#pragma unroll
    for (int d = 0; d < 32; d++) acc += xs[h * 32 + d] * wsm[h * 1024 + d * 32 + k];
    out[(size_t)n * 256 + threadIdx.x] = acc;
  }
}

// ---------------- CSR build: histogram / scan / scatter ----------------
__global__ void hist_kernel(const int* __restrict__ dst, int* __restrict__ counts, int E) {
  int e = blockIdx.x * blockDim.x + threadIdx.x;
  if (e < E) atomicAdd(&counts[dst[e]], 1);
}

__global__ __launch_bounds__(1024) void scan_kernel(
    const int* __restrict__ counts, int* __restrict__ offsets, int N)
{
  __shared__ int tile[1024];
  __shared__ int carry;
  if (threadIdx.x == 0) carry = 0;
  __syncthreads();
  for (int base = 0; base < N; base += 1024) {
    int i = base + threadIdx.x;
    int v = (i < N) ? counts[i] : 0;
    tile[threadIdx.x] = v;
    __syncthreads();
#pragma unroll
    for (int o = 1; o < 1024; o <<= 1) {
      int add = (threadIdx.x >= o) ? tile[threadIdx.x - o] : 0;
      __syncthreads();
      tile[threadIdx.x] += add;
      __syncthreads();
    }
    if (i < N) offsets[i] = carry + tile[threadIdx.x] - v;  // exclusive
    __syncthreads();
    if (threadIdx.x == 1023) carry += tile[1023];
    __syncthreads();
  }
  if (threadIdx.x == 0) offsets[N] = carry;
}

__global__ void scatter_kernel(const int* __restrict__ dst, const int* __restrict__ offsets,
                               int* __restrict__ cursor, int* __restrict__ sorted_e, int E) {
  int e = blockIdx.x * blockDim.x + threadIdx.x;
  if (e < E) {
    int d = dst[e];
    int pos = offsets[d] + atomicAdd(&cursor[d], 1);
    sorted_e[pos] = e;
  }
}

// ---------------- edge attention logit (no atomics) ----------------
__global__ __launch_bounds__(256) void edge_att(
    const float* __restrict__ q, const float* __restrict__ khat,
    const int* __restrict__ src, const int* __restrict__ dst,
    const float* __restrict__ pri, float* __restrict__ att, int E)
{
  int t = blockIdx.x * blockDim.x + threadIdx.x;
  if (t >= E * 8) return;
  int e = t >> 3, h = t & 7;
  int sN = src[e], dN = dst[e];
  const float4* qp = (const float4*)(q + (size_t)dN * 256 + h * 32);
  const float4* kp = (const float4*)(khat + (size_t)sN * 256 + h * 32);
  float acc = 0.f;
#pragma unroll
  for (int i = 0; i < 8; i++) {
    float4 a = qp[i], b = kp[i];
    acc += a.x * b.x + a.y * b.y + a.z * b.z + a.w * b.w;
  }
  att[t] = acc * pri[h] * 0.17677669529663687f;  // 1/sqrt(32)
}

// ---------------- segment softmax + aggregation (one wave per dst node) ----------------
__global__ __launch_bounds__(256) void seg_softmax_agg(
    const float* __restrict__ att, const float* __restrict__ vhat,
    const int* __restrict__ src, const int* __restrict__ sorted_e,
    const int* __restrict__ offsets, float* __restrict__ agg, int Ndst)
{
  int node = blockIdx.x * 4 + (threadIdx.x >> 6);
  if (node >= Ndst) return;
  int lane = threadIdx.x & 63;
  int h = lane >> 3;                 // head for this lane's channels
  int r0 = offsets[node], r1 = offsets[node + 1];
  float4 acc = make_float4(0.f, 0.f, 0.f, 0.f);
  if (r0 < r1) {
    float m = -INFINITY;
    for (int i = r0; i < r1; i++)
      m = fmaxf(m, att[(size_t)sorted_e[i] * 8 + h]);
    float s = 0.f;
    for (int i = r0; i < r1; i++)
      s += __expf(att[(size_t)sorted_e[i] * 8 + h] - m);
    float inv = 1.f / fmaxf(s, 1e-9f);
    for (int i = r0; i < r1; i++) {
      int e = sorted_e[i];
      float coef = __expf(att[(size_t)e * 8 + h] - m) * inv;
      float4 v = *(const float4*)(vhat + (size_t)src[e] * 256 + lane * 4);
      acc.x += coef * v.x; acc.y += coef * v.y;
      acc.z += coef * v.z; acc.w += coef * v.w;
    }
  }
  *(float4*)(agg + (size_t)node * 256 + lane * 4) = acc;
}

// ---------------- relu + optional second etype + mean scale ----------------
__global__ void relu_mean(const float* __restrict__ a, const float* __restrict__ b,
                          float* __restrict__ out, float scale, int n)
{
  int i = blockIdx.x * blockDim.x + threadIdx.x;
  if (i >= n) return;
  float v = fmaxf(a[i], 0.f);
  if (b) v += fmaxf(b[i], 0.f);
  out[i] = v * scale;
}

// ---------------- skip-blend + LayerNorm ----------------
__global__ __launch_bounds__(256) void skip_ln(
    const float* __restrict__ trans, const float* __restrict__ feat,
    const float* __restrict__ skip, int skipIdx,
    const float* __restrict__ gamma, const float* __restrict__ beta,
    float* __restrict__ out)
{
  int row = blockIdx.x;
  int tid = threadIdx.x;
  float a = 1.f / (1.f + expf(-skip[skipIdx]));
  size_t idx = (size_t)row * 256 + tid;
  float x = trans[idx] * a + feat[idx] * (1.f - a);
  __shared__ float red[4];
  int lane = tid & 63, wid = tid >> 6;
  float sum = x;
#pragma unroll
  for (int o = 32; o > 0; o >>= 1) sum += __shfl_down(sum, o, 64);
  if (lane == 0) red[wid] = sum;
  __syncthreads();
  float mu = (red[0] + red[1] + red[2] + red[3]) * (1.f / 256.f);
  float d = x - mu;
  float vs = d * d;
#pragma unroll
  for (int o = 32; o > 0; o >>= 1) vs += __shfl_down(vs, o, 64);
  __syncthreads();
  if (lane == 0) red[wid] = vs;
  __syncthreads();
  float var = (red[0] + red[1] + red[2] + red[3]) * (1.f / 256.f);
  out[idx] = d * rsqrtf(var + 1e-5f) * gamma[tid] + beta[tid];
}

extern "C" void kernel_launch(void* const* d_in, const int* in_sizes, int n_in,
                              void* d_out, int out_size, void* d_ws, size_t ws_size,
                              hipStream_t stream) {
  const float* feat_w = (const float*)d_in[0];
  const float* feat_t = (const float*)d_in[1];
  const float* feat_d = (const float*)d_in[2];
  const float* Wk = (const float*)d_in[3];
  const float* bk = (const float*)d_in[4];
  const float* Wq = (const float*)d_in[5];
  const float* bq = (const float*)d_in[6];
  const float* Wv = (const float*)d_in[7];
  const float* bv = (const float*)d_in[8];
  const float* Wa = (const float*)d_in[9];
  const float* ba = (const float*)d_in[10];
  const float* ln_scale = (const float*)d_in[11];
  const float* ln_bias = (const float*)d_in[12];
  const float* skip = (const float*)d_in[13];
  const float* rel_pri = (const float*)d_in[14];
  const float* rel_att = (const float*)d_in[15];
  const float* rel_msg = (const float*)d_in[16];
  const int* src_ww = (const int*)d_in[17];
  const int* dst_ww = (const int*)d_in[18];
  const int* src_wt = (const int*)d_in[19];
  const int* dst_wt = (const int*)d_in[20];
  const int* src_wd = (const int*)d_in[21];
  const int* dst_wd = (const int*)d_in[22];
  const int* src_tt = (const int*)d_in[23];
  const int* dst_tt = (const int*)d_in[24];
  const int* src_td = (const int*)d_in[25];
  const int* dst_td = (const int*)d_in[26];
  float* out = (float*)d_out;
  float* ws = (float*)d_ws;

  // workspace layout (floats)
  float* q_w    = ws;                  // 5,120,000
  float* q_t    = q_w + 5120000;       //   512,000
  float* q_d    = q_t + 512000;        // 1,280,000
  float* kbuf   = q_d + 1280000;       // 5,120,000
  float* vbuf   = kbuf + 5120000;      // 5,120,000
  float* khat   = vbuf + 5120000;      // 5,120,000
  float* vhat   = khat + 5120000;      // 5,120,000
  float* agg_ww = vhat + 5120000;      // 5,120,000
  float* agg_wt = agg_ww + 5120000;    //   512,000
  float* agg_wd = agg_wt + 512000;     // 1,280,000
  float* agg_tt = agg_wd + 1280000;    //   512,000
  float* agg_td = agg_tt + 512000;     // 1,280,000
  float* attb   = agg_td + 1280000;    // 1,200,000 (max E*8)
  // int scratch for CSR build (after float region)
  int* counts   = (int*)(attb + 1200000);  // 20,000
  int* cursor   = counts + 20000;          // 20,000 (adjacent -> one memset)
  int* offsets  = cursor + 20000;          // 20,001
  int* sorted_e = offsets + 20001;         // 150,000

  dim3 b256(256);
  auto cdiv = [](int a, int b) { return (a + b - 1) / b; };

  // projections
  gemm_bias256<<<dim3(cdiv(NW, 64), 4), b256, 0, stream>>>(feat_w, Wq, bq, q_w, NW);
  gemm_bias256<<<dim3(cdiv(NT, 64), 4), b256, 0, stream>>>(feat_t, Wq + 65536, bq + 256, q_t, NT);
  gemm_bias256<<<dim3(cdiv(ND, 64), 4), b256, 0, stream>>>(feat_d, Wq + 2 * 65536, bq + 512, q_d, ND);
  gemm_bias256<<<dim3(cdiv(NW, 64), 4), b256, 0, stream>>>(feat_w, Wk, bk, kbuf, NW);
  gemm_bias256<<<dim3(cdiv(NW, 64), 4), b256, 0, stream>>>(feat_w, Wv, bv, vbuf, NW);

  auto do_rel = [&](int r, int Nsrc, int Ndst, const int* srcI, const int* dstI, int E,
                    const float* qbuf, float* agg) {
    head_transform<<<cdiv(Nsrc, 16), b256, 0, stream>>>(kbuf, rel_att + (size_t)r * 8192, khat, Nsrc);
    head_transform<<<cdiv(Nsrc, 16), b256, 0, stream>>>(vbuf, rel_msg + (size_t)r * 8192, vhat, Nsrc);
    // CSR build
    hipMemsetAsync(counts, 0, (size_t)2 * 20000 * sizeof(int), stream);  // counts+cursor
    hist_kernel<<<cdiv(E, 256), b256, 0, stream>>>(dstI, counts, E);
    scan_kernel<<<1, 1024, 0, stream>>>(counts, offsets, Ndst);
    scatter_kernel<<<cdiv(E, 256), b256, 0, stream>>>(dstI, offsets, cursor, sorted_e, E);
    // attention logits + segment softmax-aggregate
    edge_att<<<cdiv(E * 8, 256), b256, 0, stream>>>(qbuf, khat, srcI, dstI, rel_pri + r * 8, attb, E);
    seg_softmax_agg<<<cdiv(Ndst, 4), b256, 0, stream>>>(attb, vhat, srcI, sorted_e, offsets, agg, Ndst);
  };

  // word-source relations
  do_rel(0, NW, NW, src_ww, dst_ww, E_WW, q_w, agg_ww);
  do_rel(1, NW, NT, src_wt, dst_wt, E_WT, q_t, agg_wt);
  do_rel(2, NW, ND, src_wd, dst_wd, E_WD, q_d, agg_wd);
  // topic-source relations
  gemm_bias256<<<dim3(cdiv(NT, 64), 4), b256, 0, stream>>>(feat_t, Wk + 65536, bk + 256, kbuf, NT);
  gemm_bias256<<<dim3(cdiv(NT, 64), 4), b256, 0, stream>>>(feat_t, Wv + 65536, bv + 256, vbuf, NT);
  do_rel(3, NT, NT, src_tt, dst_tt, E_TT, q_t, agg_tt);
  do_rel(4, NT, ND, src_td, dst_td, E_TD, q_d, agg_td);

  // relu + cross-etype mean (reuse khat/vhat as t buffers)
  float* t_word  = khat;
  float* t_topic = vhat;
  float* t_doc   = vhat + 512000;
  relu_mean<<<cdiv(NW * 256, 256), b256, 0, stream>>>(agg_ww, (const float*)nullptr, t_word, 1.0f, NW * 256);
  relu_mean<<<cdiv(NT * 256, 256), b256, 0, stream>>>(agg_wt, agg_tt, t_topic, 0.5f, NT * 256);
  relu_mean<<<cdiv(ND * 256, 256), b256, 0, stream>>>(agg_wd, agg_td, t_doc, 0.5f, ND * 256);

  // output transform (reuse kbuf/vbuf as trans buffers)
  float* tr_w = kbuf;
  float* tr_t = vbuf;
  float* tr_d = vbuf + 512000;
  gemm_bias256<<<dim3(cdiv(NW, 64), 4), b256, 0, stream>>>(t_word, Wa, ba, tr_w, NW);
  gemm_bias256<<<dim3(cdiv(NT, 64), 4), b256, 0, stream>>>(t_topic, Wa + 65536, ba + 256, tr_t, NT);
  gemm_bias256<<<dim3(cdiv(ND, 64), 4), b256, 0, stream>>>(t_doc, Wa + 2 * 65536, ba + 512, tr_d, ND);

  // skip-blend + LayerNorm -> d_out
  skip_ln<<<NW, b256, 0, stream>>>(tr_w, feat_w, skip, 0, ln_scale, ln_bias, out);
  skip_ln<<<NT, b256, 0, stream>>>(tr_t, feat_t, skip, 1, ln_scale + 256, ln_bias + 256, out + (size_t)NW * 256);
  skip_ln<<<ND, b256, 0, stream>>>(tr_d, feat_d, skip, 2, ln_scale + 512, ln_bias + 512, out + (size_t)(NW + NT) * 256);

  (void)in_sizes; (void)n_in; (void)out_size; (void)ws_size;
}

// Round 4
// 446.506 us; speedup vs baseline: 4.4562x; 2.2920x over previous
//
#include <hip/hip_runtime.h>

static constexpr int NW = 20000, NT = 2000, ND = 5000;
static constexpr int E_WW = 150000, E_WT = 80000, E_WD = 80000, E_TT = 20000, E_TD = 40000;

typedef short bf16x8 __attribute__((ext_vector_type(8)));
typedef float f32x4 __attribute__((ext_vector_type(4)));
typedef unsigned short ushort8v __attribute__((ext_vector_type(8)));

__device__ __forceinline__ unsigned short f2bf(float f) {
  union { float f; unsigned int u; } c; c.f = f;
  unsigned int u = c.u;
  u += 0x7fffu + ((u >> 16) & 1u);
  return (unsigned short)(u >> 16);
}
__device__ __forceinline__ float bf2f(unsigned short h) {
  union { unsigned int u; float f; } c; c.u = ((unsigned int)h) << 16; return c.f;
}

// ---------------- f32 -> bf16 conversion (x4 vectorized) ----------------
__global__ void f2bf_arr(const float4* __restrict__ in, ushort4* __restrict__ out, int n4) {
  int i = blockIdx.x * blockDim.x + threadIdx.x;
  if (i >= n4) return;
  float4 v = in[i];
  ushort4 o; o.x = f2bf(v.x); o.y = f2bf(v.y); o.z = f2bf(v.z); o.w = f2bf(v.w);
  out[i] = o;
}

// ---------------- W[m][k][n] f32 -> WT[m][n][k] bf16 ----------------
__global__ __launch_bounds__(256) void pack_wt(const float* __restrict__ W,
                                               unsigned short* __restrict__ WT, int nmat) {
  __shared__ float tile[32][33];
  int m = blockIdx.x, bk = blockIdx.y * 32, bn = blockIdx.z * 32;
  int tx = threadIdx.x & 31, ty = threadIdx.x >> 5;
#pragma unroll
  for (int i = 0; i < 32; i += 8)
    tile[ty + i][tx] = W[(size_t)m * 65536 + (size_t)(bk + ty + i) * 256 + bn + tx];
  __syncthreads();
#pragma unroll
  for (int i = 0; i < 32; i += 8)
    WT[(size_t)m * 65536 + (size_t)(bn + ty + i) * 256 + bk + tx] = f2bf(tile[tx][ty + i]);
}

// ---------------- rel head weights (nmat x 8 x 32 x 32 f32) -> MFMA B-frag order bf16 ----
// out[(m*16 + h*2+c)*512 + lane*8 + j] = bf16(w[m][h][k][n]), k=(lane>>4)*8+j, n=c*16+(lane&15)
__global__ void pack_headw(const float* __restrict__ w, unsigned short* __restrict__ out, int nmat) {
  int t = blockIdx.x * blockDim.x + threadIdx.x;
  if (t >= nmat * 8192) return;
  int m = t >> 13, rem = t & 8191;
  int hc = rem >> 9, idx = rem & 511;
  int lane = idx >> 3, j = idx & 7;
  int h = hc >> 1, c = hc & 1;
  int k = (lane >> 4) * 8 + j, n = c * 16 + (lane & 15);
  out[t] = f2bf(w[(size_t)m * 8192 + h * 1024 + k * 32 + n]);
}

// ---------------- MFMA GEMM: C[M,256] = A[M,256](bf16) @ W(256,256) + bias ----------------
// WT is [256][256] bf16 with WT[n][k] = W[k][n]. OUTBF: 1 -> bf16 out, 0 -> f32 out.
template <int OUTBF>
__global__ __launch_bounds__(256) void gemm_mfma(
    const unsigned short* __restrict__ A, const unsigned short* __restrict__ WT,
    const float* __restrict__ bias, float* __restrict__ Cf,
    unsigned short* __restrict__ Ch, int M) {
  __shared__ unsigned short As[64 * 64];
  __shared__ unsigned short Bs[64 * 64];
  const int bm = blockIdx.x * 64, bn = blockIdx.y * 64;
  const int tid = threadIdx.x, wave = tid >> 6, lane = tid & 63;
  f32x4 acc[4] = {};
  const int ar = wave * 16 + (lane & 15);
  const int swz = lane & 7;  // == ar&7 and br&7
  for (int k0 = 0; k0 < 256; k0 += 64) {
#pragma unroll
    for (int i = 0; i < 2; i++) {
      int c = tid + i * 256;
      int row = c >> 3, sl = c & 7;
      int srow = bm + row;
      bf16x8 av{};
      if (srow < M) av = *(const bf16x8*)(A + (size_t)srow * 256 + k0 + sl * 8);
      *(bf16x8*)&As[row * 64 + (sl ^ (row & 7)) * 8] = av;
      bf16x8 bv = *(const bf16x8*)(WT + (size_t)(bn + row) * 256 + k0 + sl * 8);
      *(bf16x8*)&Bs[row * 64 + (sl ^ (row & 7)) * 8] = bv;
    }
    __syncthreads();
#pragma unroll
    for (int kk = 0; kk < 2; kk++) {
      int slot = kk * 4 + (lane >> 4);
      bf16x8 a = *(const bf16x8*)&As[ar * 64 + ((slot ^ swz) * 8)];
#pragma unroll
      for (int nf = 0; nf < 4; nf++) {
        int br = nf * 16 + (lane & 15);
        bf16x8 b = *(const bf16x8*)&Bs[br * 64 + ((slot ^ swz) * 8)];
        acc[nf] = __builtin_amdgcn_mfma_f32_16x16x32_bf16(a, b, acc[nf], 0, 0, 0);
      }
    }
    __syncthreads();
  }
  const int col = lane & 15;
#pragma unroll
  for (int nf = 0; nf < 4; nf++) {
    float bsv = bias[bn + nf * 16 + col];
#pragma unroll
    for (int rr = 0; rr < 4; rr++) {
      int row = bm + wave * 16 + (lane >> 4) * 4 + rr;
      if (row < M) {
        float v = acc[nf][rr] + bsv;
        if (OUTBF) Ch[(size_t)row * 256 + bn + nf * 16 + col] = f2bf(v);
        else       Cf[(size_t)row * 256 + bn + nf * 16 + col] = v;
      }
    }
  }
}

// ---------------- per-node per-head 32x32 transform via MFMA (k and v fused) ----------------
__global__ __launch_bounds__(256) void head_transform_mfma(
    const unsigned short* __restrict__ kin, const unsigned short* __restrict__ vin,
    const unsigned short* __restrict__ wkp, const unsigned short* __restrict__ wvp,
    unsigned short* __restrict__ khat, unsigned short* __restrict__ vhat, int N) {
  int wave = threadIdx.x >> 6, lane = threadIdx.x & 63;
  int r0 = blockIdx.x * 64 + wave * 16;
  int arow = r0 + (lane & 15);
  bool valid = arow < N;
  int kofs = (lane >> 4) * 8;
  f32x4 z{};
#pragma unroll
  for (int h = 0; h < 8; h++) {
    bf16x8 ak{}, avv{};
    if (valid) {
      ak  = *(const bf16x8*)(kin + (size_t)arow * 256 + h * 32 + kofs);
      avv = *(const bf16x8*)(vin + (size_t)arow * 256 + h * 32 + kofs);
    }
#pragma unroll
    for (int c = 0; c < 2; c++) {
      bf16x8 bk = *(const bf16x8*)(wkp + ((h * 2 + c) * 64 + lane) * 8);
      bf16x8 bv = *(const bf16x8*)(wvp + ((h * 2 + c) * 64 + lane) * 8);
      f32x4 ok = __builtin_amdgcn_mfma_f32_16x16x32_bf16(ak, bk, z, 0, 0, 0);
      f32x4 ov = __builtin_amdgcn_mfma_f32_16x16x32_bf16(avv, bv, z, 0, 0, 0);
      int col = h * 32 + c * 16 + (lane & 15);
#pragma unroll
      for (int rr = 0; rr < 4; rr++) {
        int row = r0 + (lane >> 4) * 4 + rr;
        if (row < N) {
          khat[(size_t)row * 256 + col] = f2bf(ok[rr]);
          vhat[(size_t)row * 256 + col] = f2bf(ov[rr]);
        }
      }
    }
  }
}

// ---------------- fused CSR build over all 5 relations ----------------
struct CsrDesc {
  const int* dst[5];
  const int* src[5];
  int E[5], N[5], cbase[5], obase[5], ebase[5];
};

__global__ void hist5(CsrDesc d, int* __restrict__ counts) {
  int t = blockIdx.x * blockDim.x + threadIdx.x;
  int r = 0, base = 0;
  while (r < 5 && t >= base + d.E[r]) { base += d.E[r]; r++; }
  if (r >= 5) return;
  int e = t - base;
  atomicAdd(counts + d.cbase[r] + d.dst[r][e], 1);
}

__global__ __launch_bounds__(1024) void scan5(const int* __restrict__ counts,
                                              int* __restrict__ offsets, CsrDesc d) {
  int r = blockIdx.x;
  int N = d.N[r];
  const int* cnt = counts + d.cbase[r];
  int* off = offsets + d.obase[r];
  __shared__ int wtot[16];
  __shared__ int carry_s;
  int tid = threadIdx.x, lane = tid & 63, w = tid >> 6;
  if (tid == 0) carry_s = 0;
  __syncthreads();
  for (int base = 0; base < N; base += 1024) {
    int i = base + tid;
    int v = (i < N) ? cnt[i] : 0;
    int x = v;
#pragma unroll
    for (int dlt = 1; dlt < 64; dlt <<= 1) {
      int t = __shfl_up(x, dlt, 64);
      if (lane >= dlt) x += t;
    }
    if (lane == 63) wtot[w] = x;
    __syncthreads();
    if (w == 0) {
      int y = (lane < 16) ? wtot[lane] : 0;
#pragma unroll
      for (int dlt = 1; dlt < 16; dlt <<= 1) {
        int t = __shfl_up(y, dlt, 64);
        if (lane >= dlt) y += t;
      }
      if (lane < 16) wtot[lane] = y;
    }
    __syncthreads();
    int wpre = (w > 0) ? wtot[w - 1] : 0;
    int incl = carry_s + wpre + x;
    if (i < N) off[i] = incl - v;  // exclusive
    __syncthreads();
    if (tid == 1023) carry_s = incl;
    __syncthreads();
  }
  if (threadIdx.x == 0) off[N] = carry_s;
}

__global__ void scatter5(CsrDesc d, const int* __restrict__ offsets, int* __restrict__ cursor,
                         int* __restrict__ ssrc, int* __restrict__ sdst) {
  int t = blockIdx.x * blockDim.x + threadIdx.x;
  int r = 0, base = 0;
  while (r < 5 && t >= base + d.E[r]) { base += d.E[r]; r++; }
  if (r >= 5) return;
  int e = t - base;
  int dn = d.dst[r][e];
  int pos = offsets[d.obase[r] + dn] + atomicAdd(cursor + d.cbase[r] + dn, 1);
  ssrc[d.ebase[r] + pos] = d.src[r][e];
  sdst[d.ebase[r] + pos] = dn;
}

// ---------------- attention logits in CSR order ----------------
__global__ __launch_bounds__(256) void edge_att_sorted(
    const unsigned short* __restrict__ q, const unsigned short* __restrict__ khat,
    const int* __restrict__ ssrc, const int* __restrict__ sdst,
    const float* __restrict__ pri, float* __restrict__ att, int E) {
  int t = blockIdx.x * blockDim.x + threadIdx.x;
  if (t >= E * 8) return;
  int i = t >> 3, h = t & 7;
  int sN = ssrc[i], dN = sdst[i];
  const unsigned short* qp = q + (size_t)dN * 256 + h * 32;
  const unsigned short* kp = khat + (size_t)sN * 256 + h * 32;
  float acc = 0.f;
#pragma unroll
  for (int c = 0; c < 4; c++) {
    ushort8v a = *(const ushort8v*)(qp + c * 8);
    ushort8v b = *(const ushort8v*)(kp + c * 8);
#pragma unroll
    for (int j = 0; j < 8; j++) acc += bf2f(a[j]) * bf2f(b[j]);
  }
  att[t] = acc * pri[h] * 0.17677669529663687f;  // 1/sqrt(32)
}

// ---------------- segment softmax + aggregation (persistent waves, 2 passes) ----------------
__global__ __launch_bounds__(256) void seg_softmax_agg(
    const float* __restrict__ att, const unsigned short* __restrict__ vhat,
    const int* __restrict__ ssrc, const int* __restrict__ offsets,
    float* __restrict__ agg, int Ndst) {
  int wid = (blockIdx.x * 256 + threadIdx.x) >> 6;
  int nwaves = (gridDim.x * 256) >> 6;
  int lane = threadIdx.x & 63;
  int h = lane >> 3, j = lane & 7;
  for (int node = wid; node < Ndst; node += nwaves) {
    int r0 = offsets[node], r1 = offsets[node + 1];
    float4 acc = make_float4(0.f, 0.f, 0.f, 0.f);
    if (r0 < r1) {
      // pass A: 8-way parallel max within head group
      float m = -INFINITY;
      for (int i = r0 + j; i < r1; i += 8)
        m = fmaxf(m, att[(size_t)i * 8 + h]);
      m = fmaxf(m, __shfl_xor(m, 1, 64));
      m = fmaxf(m, __shfl_xor(m, 2, 64));
      m = fmaxf(m, __shfl_xor(m, 4, 64));
      // pass B: fused exp-sum + weighted accumulate
      float s = 0.f;
      for (int i = r0; i < r1; i++) {
        float w = __expf(att[(size_t)i * 8 + h] - m);
        s += w;
        ushort4 v = *(const ushort4*)(vhat + (size_t)ssrc[i] * 256 + lane * 4);
        acc.x += w * bf2f(v.x); acc.y += w * bf2f(v.y);
        acc.z += w * bf2f(v.z); acc.w += w * bf2f(v.w);
      }
      float inv = 1.f / fmaxf(s, 1e-9f);
      acc.x *= inv; acc.y *= inv; acc.z *= inv; acc.w *= inv;
    }
    *(float4*)(agg + (size_t)node * 256 + lane * 4) = acc;
  }
}

// ---------------- relu + optional second etype + mean scale -> bf16 ----------------
__global__ void relu_mean_h(const float4* __restrict__ a, const float4* __restrict__ b,
                            ushort4* __restrict__ out, float scale, int n4) {
  int i = blockIdx.x * blockDim.x + threadIdx.x;
  if (i >= n4) return;
  float4 va = a[i];
  float4 r;
  r.x = fmaxf(va.x, 0.f); r.y = fmaxf(va.y, 0.f);
  r.z = fmaxf(va.z, 0.f); r.w = fmaxf(va.w, 0.f);
  if (b) {
    float4 vb = b[i];
    r.x += fmaxf(vb.x, 0.f); r.y += fmaxf(vb.y, 0.f);
    r.z += fmaxf(vb.z, 0.f); r.w += fmaxf(vb.w, 0.f);
  }
  ushort4 o;
  o.x = f2bf(r.x * scale); o.y = f2bf(r.y * scale);
  o.z = f2bf(r.z * scale); o.w = f2bf(r.w * scale);
  out[i] = o;
}

// ---------------- skip-blend + LayerNorm ----------------
__global__ __launch_bounds__(256) void skip_ln(
    const float* __restrict__ trans, const float* __restrict__ feat,
    const float* __restrict__ skip, int skipIdx,
    const float* __restrict__ gamma, const float* __restrict__ beta,
    float* __restrict__ out) {
  int row = blockIdx.x;
  int tid = threadIdx.x;
  float a = 1.f / (1.f + expf(-skip[skipIdx]));
  size_t idx = (size_t)row * 256 + tid;
  float x = trans[idx] * a + feat[idx] * (1.f - a);
  __shared__ float red[4];
  int lane = tid & 63, wid = tid >> 6;
  float sum = x;
#pragma unroll
  for (int o = 32; o > 0; o >>= 1) sum += __shfl_down(sum, o, 64);
  if (lane == 0) red[wid] = sum;
  __syncthreads();
  float mu = (red[0] + red[1] + red[2] + red[3]) * (1.f / 256.f);
  float d = x - mu;
  float vs = d * d;
#pragma unroll
  for (int o = 32; o > 0; o >>= 1) vs += __shfl_down(vs, o, 64);
  __syncthreads();
  if (lane == 0) red[wid] = vs;
  __syncthreads();
  float var = (red[0] + red[1] + red[2] + red[3]) * (1.f / 256.f);
  out[idx] = d * rsqrtf(var + 1e-5f) * gamma[tid] + beta[tid];
}

extern "C" void kernel_launch(void* const* d_in, const int* in_sizes, int n_in,
                              void* d_out, int out_size, void* d_ws, size_t ws_size,
                              hipStream_t stream) {
  const float* feat_w = (const float*)d_in[0];
  const float* feat_t = (const float*)d_in[1];
  const float* feat_d = (const float*)d_in[2];
  const float* Wk = (const float*)d_in[3];
  const float* bk = (const float*)d_in[4];
  const float* Wq = (const float*)d_in[5];
  const float* bq = (const float*)d_in[6];
  const float* Wv = (const float*)d_in[7];
  const float* bv = (const float*)d_in[8];
  const float* Wa = (const float*)d_in[9];
  const float* ba = (const float*)d_in[10];
  const float* ln_scale = (const float*)d_in[11];
  const float* ln_bias = (const float*)d_in[12];
  const float* skip = (const float*)d_in[13];
  const float* rel_pri = (const float*)d_in[14];
  const float* rel_att = (const float*)d_in[15];
  const float* rel_msg = (const float*)d_in[16];
  const int* src_ww = (const int*)d_in[17];
  const int* dst_ww = (const int*)d_in[18];
  const int* src_wt = (const int*)d_in[19];
  const int* dst_wt = (const int*)d_in[20];
  const int* src_wd = (const int*)d_in[21];
  const int* dst_wd = (const int*)d_in[22];
  const int* src_tt = (const int*)d_in[23];
  const int* dst_tt = (const int*)d_in[24];
  const int* src_td = (const int*)d_in[25];
  const int* dst_td = (const int*)d_in[26];
  float* out = (float*)d_out;
  float* ws = (float*)d_ws;

  // ---- workspace layout (ALL allocF sizes are in FLOAT units) ----
  size_t off = 0;
  auto allocF = [&](size_t nf) { float* p = ws + off; off += nf; return p; };
  // region A: q bf16
  unsigned short* q_w_h = (unsigned short*)allocF(2560000);
  unsigned short* q_t_h = (unsigned short*)allocF(256000);
  unsigned short* q_d_h = (unsigned short*)allocF(640000);
  // region B: k/v bf16 (word + topic)
  unsigned short* k_w_h = (unsigned short*)allocF(2560000);
  unsigned short* v_w_h = (unsigned short*)allocF(2560000);
  unsigned short* k_t_h = (unsigned short*)allocF(256000);
  unsigned short* v_t_h = (unsigned short*)allocF(256000);
  // region C: khat/vhat bf16 (per-rel, reused); later reused as t bf16 buffers
  float* regC = allocF(5120000);
  unsigned short* khat_h = (unsigned short*)regC;
  unsigned short* vhat_h = (unsigned short*)(regC + 2560000);
  unsigned short* t_word_h  = (unsigned short*)regC;
  unsigned short* t_topic_h = (unsigned short*)(regC + 2560000);
  unsigned short* t_doc_h   = (unsigned short*)(regC + 2816000);
  // region D: agg f32
  float* agg_ww = allocF(5120000);
  float* agg_wt = allocF(512000);
  float* agg_wd = allocF(1280000);
  float* agg_tt = allocF(512000);
  float* agg_td = allocF(1280000);
  // region E: union(feat bf16 + attb | tr f32)
  float* regE = allocF(6912000);
  unsigned short* feat_w_h = (unsigned short*)regE;
  unsigned short* feat_t_h = (unsigned short*)(regE + 2560000);
  unsigned short* feat_d_h = (unsigned short*)(regE + 2816000);
  float* attb = regE + 3456000;
  float* tr_w = regE;
  float* tr_t = regE + 5120000;
  float* tr_d = regE + 5632000;
  // region F: packed weights -- sizes in FLOATS (each 256x256 bf16 mat = 32768 floats)
  unsigned short* WTq = (unsigned short*)allocF(98304);   // 3 mats * 65536 ushorts
  unsigned short* WTk = (unsigned short*)allocF(65536);   // 2 mats
  unsigned short* WTv = (unsigned short*)allocF(65536);   // 2 mats
  unsigned short* WTa = (unsigned short*)allocF(98304);   // 3 mats
  unsigned short* wkp = (unsigned short*)allocF(20480);   // 5 rels * 8192 ushorts
  unsigned short* wvp = (unsigned short*)allocF(20480);
  // region G: CSR ints
  int* counts  = (int*)allocF(34000);
  int* cursor  = (int*)allocF(34000);
  int* offsets = (int*)allocF(34008);
  int* ssrc    = (int*)allocF(370000);
  int* sdst    = (int*)allocF(370000);

  dim3 b256(256);
  auto cdiv = [](int a, int b) { return (a + b - 1) / b; };

  // ---- conversions & weight packing ----
  f2bf_arr<<<cdiv(NW * 64, 256), b256, 0, stream>>>((const float4*)feat_w, (ushort4*)feat_w_h, NW * 64);
  f2bf_arr<<<cdiv(NT * 64, 256), b256, 0, stream>>>((const float4*)feat_t, (ushort4*)feat_t_h, NT * 64);
  f2bf_arr<<<cdiv(ND * 64, 256), b256, 0, stream>>>((const float4*)feat_d, (ushort4*)feat_d_h, ND * 64);
  pack_wt<<<dim3(3, 8, 8), b256, 0, stream>>>(Wq, WTq, 3);
  pack_wt<<<dim3(2, 8, 8), b256, 0, stream>>>(Wk, WTk, 2);
  pack_wt<<<dim3(2, 8, 8), b256, 0, stream>>>(Wv, WTv, 2);
  pack_wt<<<dim3(3, 8, 8), b256, 0, stream>>>(Wa, WTa, 3);
  pack_headw<<<160, b256, 0, stream>>>(rel_att, wkp, 5);
  pack_headw<<<160, b256, 0, stream>>>(rel_msg, wvp, 5);

  // ---- CSR build (all 5 relations) ----
  CsrDesc dsc;
  dsc.dst[0] = dst_ww; dsc.dst[1] = dst_wt; dsc.dst[2] = dst_wd; dsc.dst[3] = dst_tt; dsc.dst[4] = dst_td;
  dsc.src[0] = src_ww; dsc.src[1] = src_wt; dsc.src[2] = src_wd; dsc.src[3] = src_tt; dsc.src[4] = src_td;
  int Es[5] = {E_WW, E_WT, E_WD, E_TT, E_TD};
  int Ns[5] = {NW, NT, ND, NT, ND};
  int cb = 0, eb = 0;
  for (int r = 0; r < 5; r++) {
    dsc.E[r] = Es[r]; dsc.N[r] = Ns[r];
    dsc.cbase[r] = cb; dsc.obase[r] = cb + r; dsc.ebase[r] = eb;
    cb += Ns[r]; eb += Es[r];
  }
  hipMemsetAsync(counts, 0, (size_t)68000 * sizeof(int), stream);  // counts + cursor
  hist5<<<cdiv(370000, 256), b256, 0, stream>>>(dsc, counts);
  scan5<<<5, 1024, 0, stream>>>(counts, offsets, dsc);
  scatter5<<<cdiv(370000, 256), b256, 0, stream>>>(dsc, offsets, cursor, ssrc, sdst);

  // ---- projections (bf16 MFMA GEMMs) ----
  gemm_mfma<1><<<dim3(cdiv(NW, 64), 4), b256, 0, stream>>>(feat_w_h, WTq, bq, nullptr, q_w_h, NW);
  gemm_mfma<1><<<dim3(cdiv(NT, 64), 4), b256, 0, stream>>>(feat_t_h, WTq + 65536, bq + 256, nullptr, q_t_h, NT);
  gemm_mfma<1><<<dim3(cdiv(ND, 64), 4), b256, 0, stream>>>(feat_d_h, WTq + 131072, bq + 512, nullptr, q_d_h, ND);
  gemm_mfma<1><<<dim3(cdiv(NW, 64), 4), b256, 0, stream>>>(feat_w_h, WTk, bk, nullptr, k_w_h, NW);
  gemm_mfma<1><<<dim3(cdiv(NW, 64), 4), b256, 0, stream>>>(feat_w_h, WTv, bv, nullptr, v_w_h, NW);
  gemm_mfma<1><<<dim3(cdiv(NT, 64), 4), b256, 0, stream>>>(feat_t_h, WTk + 65536, bk + 256, nullptr, k_t_h, NT);
  gemm_mfma<1><<<dim3(cdiv(NT, 64), 4), b256, 0, stream>>>(feat_t_h, WTv + 65536, bv + 256, nullptr, v_t_h, NT);

  // ---- per-relation attention ----
  auto do_rel = [&](int r, const unsigned short* kh, const unsigned short* vh, int Nsrc, int Ndst,
                    const unsigned short* qh, float* agg) {
    head_transform_mfma<<<cdiv(Nsrc, 64), b256, 0, stream>>>(
        kh, vh, wkp + (size_t)r * 8192, wvp + (size_t)r * 8192, khat_h, vhat_h, Nsrc);
    edge_att_sorted<<<cdiv(dsc.E[r] * 8, 256), b256, 0, stream>>>(
        qh, khat_h, ssrc + dsc.ebase[r], sdst + dsc.ebase[r], rel_pri + r * 8, attb, dsc.E[r]);
    int grid = min(cdiv(Ndst, 4), 1024);
    seg_softmax_agg<<<grid, b256, 0, stream>>>(
        attb, vhat_h, ssrc + dsc.ebase[r], offsets + dsc.obase[r], agg, Ndst);
  };
  do_rel(0, k_w_h, v_w_h, NW, NW, q_w_h, agg_ww);
  do_rel(1, k_w_h, v_w_h, NW, NT, q_t_h, agg_wt);
  do_rel(2, k_w_h, v_w_h, NW, ND, q_d_h, agg_wd);
  do_rel(3, k_t_h, v_t_h, NT, NT, q_t_h, agg_tt);
  do_rel(4, k_t_h, v_t_h, NT, ND, q_d_h, agg_td);

  // ---- relu + cross-etype mean -> bf16 t buffers (region C, khat/vhat dead) ----
  relu_mean_h<<<cdiv(NW * 64, 256), b256, 0, stream>>>((const float4*)agg_ww, nullptr,
                                                       (ushort4*)t_word_h, 1.0f, NW * 64);
  relu_mean_h<<<cdiv(NT * 64, 256), b256, 0, stream>>>((const float4*)agg_wt, (const float4*)agg_tt,
                                                       (ushort4*)t_topic_h, 0.5f, NT * 64);
  relu_mean_h<<<cdiv(ND * 64, 256), b256, 0, stream>>>((const float4*)agg_wd, (const float4*)agg_td,
                                                       (ushort4*)t_doc_h, 0.5f, ND * 64);

  // ---- output transform (f32 out, region E; attb/feat_h dead) ----
  gemm_mfma<0><<<dim3(cdiv(NW, 64), 4), b256, 0, stream>>>(t_word_h, WTa, ba, tr_w, nullptr, NW);
  gemm_mfma<0><<<dim3(cdiv(NT, 64), 4), b256, 0, stream>>>(t_topic_h, WTa + 65536, ba + 256, tr_t, nullptr, NT);
  gemm_mfma<0><<<dim3(cdiv(ND, 64), 4), b256, 0, stream>>>(t_doc_h, WTa + 131072, ba + 512, tr_d, nullptr, ND);

  // ---- skip-blend + LayerNorm -> d_out ----
  skip_ln<<<NW, b256, 0, stream>>>(tr_w, feat_w, skip, 0, ln_scale, ln_bias, out);
  skip_ln<<<NT, b256, 0, stream>>>(tr_t, feat_t, skip, 1, ln_scale + 256, ln_bias + 256, out + (size_t)NW * 256);
  skip_ln<<<ND, b256, 0, stream>>>(tr_d, feat_d, skip, 2, ln_scale + 512, ln_bias + 512, out + (size_t)(NW + NT) * 256);

  (void)in_sizes; (void)n_in; (void)out_size; (void)ws_size;
}

// Round 5
// 330.362 us; speedup vs baseline: 6.0228x; 1.3516x over previous
//
#include <hip/hip_runtime.h>

static constexpr int NW = 20000, NT = 2000, ND = 5000;
static constexpr int E_WW = 150000, E_WT = 80000, E_WD = 80000, E_TT = 20000, E_TD = 40000;

typedef short bf16x8 __attribute__((ext_vector_type(8)));
typedef float f32x4 __attribute__((ext_vector_type(4)));

__device__ __forceinline__ unsigned short f2bf(float f) {
  union { float f; unsigned int u; } c; c.f = f;
  unsigned int u = c.u;
  u += 0x7fffu + ((u >> 16) & 1u);
  return (unsigned short)(u >> 16);
}
__device__ __forceinline__ float bf2f(unsigned short h) {
  union { unsigned int u; float f; } c; c.u = ((unsigned int)h) << 16; return c.f;
}
__device__ __forceinline__ bf16x8 pack8(float4 a, float4 b) {
  bf16x8 r;
  r[0] = (short)f2bf(a.x); r[1] = (short)f2bf(a.y); r[2] = (short)f2bf(a.z); r[3] = (short)f2bf(a.w);
  r[4] = (short)f2bf(b.x); r[5] = (short)f2bf(b.y); r[6] = (short)f2bf(b.z); r[7] = (short)f2bf(b.w);
  return r;
}

// ---------------- pack 10 weight matrices: W[k][n] f32 -> WT[n][k] bf16 ----------------
struct Pack10 { const float* src[10]; unsigned short* dst[10]; };
__global__ __launch_bounds__(256) void pack_wt10(Pack10 p) {
  __shared__ float tile[32][33];
  const float* W = p.src[blockIdx.x];
  unsigned short* WT = p.dst[blockIdx.x];
  int bk = blockIdx.y * 32, bn = blockIdx.z * 32;
  int tx = threadIdx.x & 31, ty = threadIdx.x >> 5;
#pragma unroll
  for (int i = 0; i < 32; i += 8)
    tile[ty + i][tx] = W[(size_t)(bk + ty + i) * 256 + bn + tx];
  __syncthreads();
#pragma unroll
  for (int i = 0; i < 32; i += 8)
    WT[(size_t)(bn + ty + i) * 256 + bk + tx] = f2bf(tile[tx][ty + i]);
}

// ---------------- rel head weights -> MFMA B-frag order bf16 ----------------
__global__ void pack_headw(const float* __restrict__ w, unsigned short* __restrict__ out, int nmat) {
  int t = blockIdx.x * blockDim.x + threadIdx.x;
  if (t >= nmat * 8192) return;
  int m = t >> 13, rem = t & 8191;
  int hc = rem >> 9, idx = rem & 511;
  int lane = idx >> 3, j = idx & 7;
  int h = hc >> 1, c = hc & 1;
  int k = (lane >> 4) * 8 + j, n = c * 16 + (lane & 15);
  out[t] = f2bf(w[(size_t)m * 8192 + h * 1024 + k * 32 + n]);
}

// ---------------- wide projection GEMM: out[seg] = A(f32) @ WT_seg + b_seg, bf16 out ----
struct ProjArgs {
  const float* A; const unsigned short* WT;
  const float* bias[3]; unsigned short* outp[3];
  int M;
};
__global__ __launch_bounds__(256) void proj_gemm(ProjArgs pa) {
  __shared__ unsigned short As[64 * 64];
  __shared__ unsigned short Bs[64 * 64];
  const int bm = blockIdx.x * 64, bn = blockIdx.y * 64;
  const int seg = blockIdx.y >> 2;
  const int tid = threadIdx.x, wave = tid >> 6, lane = tid & 63;
  f32x4 acc[4] = {};
  const int ar = wave * 16 + (lane & 15);
  const int swz = lane & 7;
  for (int k0 = 0; k0 < 256; k0 += 64) {
#pragma unroll
    for (int i = 0; i < 2; i++) {
      int c = tid + i * 256;
      int row = c >> 3, sl = c & 7;
      int srow = bm + row;
      float4 a0 = make_float4(0.f, 0.f, 0.f, 0.f), a1 = a0;
      if (srow < pa.M) {
        a0 = *(const float4*)(pa.A + (size_t)srow * 256 + k0 + sl * 8);
        a1 = *(const float4*)(pa.A + (size_t)srow * 256 + k0 + sl * 8 + 4);
      }
      *(bf16x8*)&As[row * 64 + (sl ^ (row & 7)) * 8] = pack8(a0, a1);
      bf16x8 bv = *(const bf16x8*)(pa.WT + (size_t)(bn + row) * 256 + k0 + sl * 8);
      *(bf16x8*)&Bs[row * 64 + (sl ^ (row & 7)) * 8] = bv;
    }
    __syncthreads();
#pragma unroll
    for (int kk = 0; kk < 2; kk++) {
      int slot = kk * 4 + (lane >> 4);
      bf16x8 a = *(const bf16x8*)&As[ar * 64 + ((slot ^ swz) * 8)];
#pragma unroll
      for (int nf = 0; nf < 4; nf++) {
        int br = nf * 16 + (lane & 15);
        bf16x8 b = *(const bf16x8*)&Bs[br * 64 + ((slot ^ swz) * 8)];
        acc[nf] = __builtin_amdgcn_mfma_f32_16x16x32_bf16(a, b, acc[nf], 0, 0, 0);
      }
    }
    __syncthreads();
  }
  const int col = lane & 15;
  const float* bias = pa.bias[seg];
  unsigned short* outp = pa.outp[seg];
  const int cbk = bn & 255;
#pragma unroll
  for (int nf = 0; nf < 4; nf++) {
    float bsv = bias[cbk + nf * 16 + col];
#pragma unroll
    for (int rr = 0; rr < 4; rr++) {
      int row = bm + wave * 16 + (lane >> 4) * 4 + rr;
      if (row < pa.M)
        outp[(size_t)row * 256 + cbk + nf * 16 + col] = f2bf(acc[nf][rr] + bsv);
    }
  }
}

// ---------------- batched per-head 32x32 transform (all 5 rels, k & v) ----------------
struct HtArgs {
  const unsigned short* kin[5]; const unsigned short* vin[5];
  unsigned short* khat[5]; unsigned short* vhat[5];
  const unsigned short* wk; const unsigned short* wv;
  int N[5]; int bcum[6];
};
__global__ __launch_bounds__(256) void head_transform_all(HtArgs a) {
  int r = 0;
  while (r < 4 && (int)blockIdx.x >= a.bcum[r + 1]) r++;
  int local = blockIdx.x - a.bcum[r];
  const unsigned short* kin = a.kin[r];
  const unsigned short* vin = a.vin[r];
  unsigned short* khat = a.khat[r];
  unsigned short* vhat = a.vhat[r];
  const unsigned short* wkp = a.wk + (size_t)r * 8192;
  const unsigned short* wvp = a.wv + (size_t)r * 8192;
  int N = a.N[r];
  int wave = threadIdx.x >> 6, lane = threadIdx.x & 63;
  int r0 = local * 64 + wave * 16;
  int arow = r0 + (lane & 15);
  bool valid = arow < N;
  int kofs = (lane >> 4) * 8;
  f32x4 z{};
#pragma unroll
  for (int h = 0; h < 8; h++) {
    bf16x8 ak{}, avv{};
    if (valid) {
      ak  = *(const bf16x8*)(kin + (size_t)arow * 256 + h * 32 + kofs);
      avv = *(const bf16x8*)(vin + (size_t)arow * 256 + h * 32 + kofs);
    }
#pragma unroll
    for (int c = 0; c < 2; c++) {
      bf16x8 bk = *(const bf16x8*)(wkp + ((h * 2 + c) * 64 + lane) * 8);
      bf16x8 bv = *(const bf16x8*)(wvp + ((h * 2 + c) * 64 + lane) * 8);
      f32x4 ok = __builtin_amdgcn_mfma_f32_16x16x32_bf16(ak, bk, z, 0, 0, 0);
      f32x4 ov = __builtin_amdgcn_mfma_f32_16x16x32_bf16(avv, bv, z, 0, 0, 0);
      int colc = h * 32 + c * 16 + (lane & 15);
#pragma unroll
      for (int rr = 0; rr < 4; rr++) {
        int row = r0 + (lane >> 4) * 4 + rr;
        if (row < N) {
          khat[(size_t)row * 256 + colc] = f2bf(ok[rr]);
          vhat[(size_t)row * 256 + colc] = f2bf(ov[rr]);
        }
      }
    }
  }
}

// ---------------- fused CSR build over all 5 relations ----------------
struct CsrDesc {
  const int* dst[5];
  const int* src[5];
  int E[5], N[5], cbase[5], obase[5], ebase[5];
};

__global__ void hist5(CsrDesc d, int* __restrict__ counts) {
  int t = blockIdx.x * blockDim.x + threadIdx.x;
  int r = 0, base = 0;
  while (r < 5 && t >= base + d.E[r]) { base += d.E[r]; r++; }
  if (r >= 5) return;
  int e = t - base;
  atomicAdd(counts + d.cbase[r] + d.dst[r][e], 1);
}

__global__ __launch_bounds__(1024) void scan5(const int* __restrict__ counts,
                                              int* __restrict__ offsets, CsrDesc d) {
  int r = blockIdx.x;
  int N = d.N[r];
  const int* cnt = counts + d.cbase[r];
  int* off = offsets + d.obase[r];
  __shared__ int wtot[16];
  __shared__ int carry_s;
  int tid = threadIdx.x, lane = tid & 63, w = tid >> 6;
  if (tid == 0) carry_s = 0;
  __syncthreads();
  for (int base = 0; base < N; base += 1024) {
    int i = base + tid;
    int v = (i < N) ? cnt[i] : 0;
    int x = v;
#pragma unroll
    for (int dlt = 1; dlt < 64; dlt <<= 1) {
      int t = __shfl_up(x, dlt, 64);
      if (lane >= dlt) x += t;
    }
    if (lane == 63) wtot[w] = x;
    __syncthreads();
    if (w == 0) {
      int y = (lane < 16) ? wtot[lane] : 0;
#pragma unroll
      for (int dlt = 1; dlt < 16; dlt <<= 1) {
        int t = __shfl_up(y, dlt, 64);
        if (lane >= dlt) y += t;
      }
      if (lane < 16) wtot[lane] = y;
    }
    __syncthreads();
    int wpre = (w > 0) ? wtot[w - 1] : 0;
    int incl = carry_s + wpre + x;
    if (i < N) off[i] = incl - v;
    __syncthreads();
    if (tid == 1023) carry_s = incl;
    __syncthreads();
  }
  if (threadIdx.x == 0) off[N] = carry_s;
}

__global__ void scatter5(CsrDesc d, const int* __restrict__ offsets, int* __restrict__ cursor,
                         int* __restrict__ ssrc) {
  int t = blockIdx.x * blockDim.x + threadIdx.x;
  int r = 0, base = 0;
  while (r < 5 && t >= base + d.E[r]) { base += d.E[r]; r++; }
  if (r >= 5) return;
  int e = t - base;
  int dn = d.dst[r][e];
  int pos = offsets[d.obase[r] + dn] + atomicAdd(cursor + d.cbase[r] + dn, 1);
  ssrc[d.ebase[r] + pos] = d.src[r][e];
}

// ---------------- fused edge attention + online segment softmax + aggregation ----------
struct AttArgs {
  const unsigned short* q[5]; const unsigned short* kh[5]; const unsigned short* vh[5];
  const int* ssrc[5]; const int* offs[5]; float* agg[5];
  const float* pri;
  int bcum[6]; int Ndst[5];
};
__global__ __launch_bounds__(256) void fused_att_agg(AttArgs a) {
  int r = 0;
  while (r < 4 && (int)blockIdx.x >= a.bcum[r + 1]) r++;
  int wave = threadIdx.x >> 6, lane = threadIdx.x & 63;
  int node = (blockIdx.x - a.bcum[r]) * 4 + wave;
  if (node >= a.Ndst[r]) return;
  const unsigned short* q = a.q[r];
  const unsigned short* kh = a.kh[r];
  const unsigned short* vh = a.vh[r];
  const int* ssrc = a.ssrc[r];
  const int* offs = a.offs[r];
  int h = lane >> 3;
  float prih = a.pri[r * 8 + h] * 0.17677669529663687f;  // pri/sqrt(32)
  int r0 = offs[node], r1 = offs[node + 1];
  float4 acc = make_float4(0.f, 0.f, 0.f, 0.f);
  if (r0 < r1) {
    ushort4 qv = *(const ushort4*)(q + (size_t)node * 256 + lane * 4);
    float q0 = bf2f(qv.x), q1 = bf2f(qv.y), q2 = bf2f(qv.z), q3 = bf2f(qv.w);
    float m = -1e30f, s = 0.f;
    for (int i = r0; i < r1; i++) {
      int sn = ssrc[i];
      ushort4 kv = *(const ushort4*)(kh + (size_t)sn * 256 + lane * 4);
      ushort4 vv = *(const ushort4*)(vh + (size_t)sn * 256 + lane * 4);
      float d = q0 * bf2f(kv.x) + q1 * bf2f(kv.y) + q2 * bf2f(kv.z) + q3 * bf2f(kv.w);
      d += __shfl_xor(d, 1, 64);
      d += __shfl_xor(d, 2, 64);
      d += __shfl_xor(d, 4, 64);
      float logit = d * prih;
      float mn = fmaxf(m, logit);
      float scale = __expf(m - mn);
      float w = __expf(logit - mn);
      m = mn;
      s = s * scale + w;
      acc.x = acc.x * scale + w * bf2f(vv.x);
      acc.y = acc.y * scale + w * bf2f(vv.y);
      acc.z = acc.z * scale + w * bf2f(vv.z);
      acc.w = acc.w * scale + w * bf2f(vv.w);
    }
    float inv = 1.f / fmaxf(s, 1e-9f);
    acc.x *= inv; acc.y *= inv; acc.z *= inv; acc.w *= inv;
  }
  *(float4*)(a.agg[r] + (size_t)node * 256 + lane * 4) = acc;
}

// ---------------- output GEMM with fused relu/mean A-load + skip-blend + LayerNorm ------
__global__ __launch_bounds__(256) void out_gemm_ln(
    const float* __restrict__ aggA, const float* __restrict__ aggB, float scale,
    const unsigned short* __restrict__ WT, const float* __restrict__ ba,
    const float* __restrict__ feat, const float* __restrict__ skipv, int skipIdx,
    const float* __restrict__ gamma, const float* __restrict__ beta,
    float* __restrict__ out, int M) {
  __shared__ unsigned short As[64 * 64];
  __shared__ unsigned short Bs[256 * 64];
  const int bm = blockIdx.x * 64;
  const int tid = threadIdx.x, wave = tid >> 6, lane = tid & 63;
  f32x4 acc[16] = {};
  const int ar = wave * 16 + (lane & 15);
  const int swz = lane & 7;
  for (int k0 = 0; k0 < 256; k0 += 64) {
#pragma unroll
    for (int i = 0; i < 2; i++) {
      int c = tid + i * 256;
      int row = c >> 3, sl = c & 7;
      int srow = bm + row;
      float4 r0 = make_float4(0.f, 0.f, 0.f, 0.f), r1 = r0;
      if (srow < M) {
        float4 a0 = *(const float4*)(aggA + (size_t)srow * 256 + k0 + sl * 8);
        float4 a1 = *(const float4*)(aggA + (size_t)srow * 256 + k0 + sl * 8 + 4);
        r0.x = fmaxf(a0.x, 0.f); r0.y = fmaxf(a0.y, 0.f); r0.z = fmaxf(a0.z, 0.f); r0.w = fmaxf(a0.w, 0.f);
        r1.x = fmaxf(a1.x, 0.f); r1.y = fmaxf(a1.y, 0.f); r1.z = fmaxf(a1.z, 0.f); r1.w = fmaxf(a1.w, 0.f);
        if (aggB) {
          float4 b0 = *(const float4*)(aggB + (size_t)srow * 256 + k0 + sl * 8);
          float4 b1 = *(const float4*)(aggB + (size_t)srow * 256 + k0 + sl * 8 + 4);
          r0.x += fmaxf(b0.x, 0.f); r0.y += fmaxf(b0.y, 0.f); r0.z += fmaxf(b0.z, 0.f); r0.w += fmaxf(b0.w, 0.f);
          r1.x += fmaxf(b1.x, 0.f); r1.y += fmaxf(b1.y, 0.f); r1.z += fmaxf(b1.z, 0.f); r1.w += fmaxf(b1.w, 0.f);
        }
        r0.x *= scale; r0.y *= scale; r0.z *= scale; r0.w *= scale;
        r1.x *= scale; r1.y *= scale; r1.z *= scale; r1.w *= scale;
      }
      *(bf16x8*)&As[row * 64 + (sl ^ (row & 7)) * 8] = pack8(r0, r1);
    }
#pragma unroll
    for (int i = 0; i < 8; i++) {
      int c = tid + i * 256;
      int row = c >> 3, sl = c & 7;
      bf16x8 bv = *(const bf16x8*)(WT + (size_t)row * 256 + k0 + sl * 8);
      *(bf16x8*)&Bs[row * 64 + (sl ^ (row & 7)) * 8] = bv;
    }
    __syncthreads();
#pragma unroll
    for (int kk = 0; kk < 2; kk++) {
      int slot = kk * 4 + (lane >> 4);
      bf16x8 a = *(const bf16x8*)&As[ar * 64 + ((slot ^ swz) * 8)];
#pragma unroll
      for (int nf = 0; nf < 16; nf++) {
        int br = nf * 16 + (lane & 15);
        bf16x8 b = *(const bf16x8*)&Bs[br * 64 + ((slot ^ swz) * 8)];
        acc[nf] = __builtin_amdgcn_mfma_f32_16x16x32_bf16(a, b, acc[nf], 0, 0, 0);
      }
    }
    __syncthreads();
  }
  const int c16 = lane & 15;
  float a_skip = 1.f / (1.f + __expf(-skipv[skipIdx]));
  float one_m = 1.f - a_skip;
  float g[16], bb[16], bia[16];
#pragma unroll
  for (int nf = 0; nf < 16; nf++) {
    g[nf] = gamma[nf * 16 + c16];
    bb[nf] = beta[nf * 16 + c16];
    bia[nf] = ba[nf * 16 + c16];
  }
#pragma unroll
  for (int rr = 0; rr < 4; rr++) {
    int row = bm + wave * 16 + (lane >> 4) * 4 + rr;
    bool valid = row < M;
#pragma unroll
    for (int nf = 0; nf < 16; nf++) {
      float fv = valid ? feat[(size_t)row * 256 + nf * 16 + c16] : 0.f;
      acc[nf][rr] = (acc[nf][rr] + bia[nf]) * a_skip + fv * one_m;
    }
    float p = 0.f;
#pragma unroll
    for (int nf = 0; nf < 16; nf++) p += acc[nf][rr];
    p += __shfl_xor(p, 1, 16); p += __shfl_xor(p, 2, 16);
    p += __shfl_xor(p, 4, 16); p += __shfl_xor(p, 8, 16);
    float mu = p * (1.f / 256.f);
    float qv = 0.f;
#pragma unroll
    for (int nf = 0; nf < 16; nf++) { float dd = acc[nf][rr] - mu; qv += dd * dd; }
    qv += __shfl_xor(qv, 1, 16); qv += __shfl_xor(qv, 2, 16);
    qv += __shfl_xor(qv, 4, 16); qv += __shfl_xor(qv, 8, 16);
    float rstd = rsqrtf(qv * (1.f / 256.f) + 1e-5f);
    if (valid) {
#pragma unroll
      for (int nf = 0; nf < 16; nf++)
        out[(size_t)row * 256 + nf * 16 + c16] = (acc[nf][rr] - mu) * rstd * g[nf] + bb[nf];
    }
  }
}

extern "C" void kernel_launch(void* const* d_in, const int* in_sizes, int n_in,
                              void* d_out, int out_size, void* d_ws, size_t ws_size,
                              hipStream_t stream) {
  const float* feat_w = (const float*)d_in[0];
  const float* feat_t = (const float*)d_in[1];
  const float* feat_d = (const float*)d_in[2];
  const float* Wk = (const float*)d_in[3];
  const float* bk = (const float*)d_in[4];
  const float* Wq = (const float*)d_in[5];
  const float* bq = (const float*)d_in[6];
  const float* Wv = (const float*)d_in[7];
  const float* bv = (const float*)d_in[8];
  const float* Wa = (const float*)d_in[9];
  const float* ba = (const float*)d_in[10];
  const float* ln_scale = (const float*)d_in[11];
  const float* ln_bias = (const float*)d_in[12];
  const float* skip = (const float*)d_in[13];
  const float* rel_pri = (const float*)d_in[14];
  const float* rel_att = (const float*)d_in[15];
  const float* rel_msg = (const float*)d_in[16];
  const int* src_ww = (const int*)d_in[17];
  const int* dst_ww = (const int*)d_in[18];
  const int* src_wt = (const int*)d_in[19];
  const int* dst_wt = (const int*)d_in[20];
  const int* src_wd = (const int*)d_in[21];
  const int* dst_wd = (const int*)d_in[22];
  const int* src_tt = (const int*)d_in[23];
  const int* dst_tt = (const int*)d_in[24];
  const int* src_td = (const int*)d_in[25];
  const int* dst_td = (const int*)d_in[26];
  float* out = (float*)d_out;
  float* ws = (float*)d_ws;

  size_t off = 0;
  auto allocF = [&](size_t nf) { float* p = ws + off; off += nf; return p; };
  unsigned short* q_w_h = (unsigned short*)allocF(2560000);
  unsigned short* q_t_h = (unsigned short*)allocF(256000);
  unsigned short* q_d_h = (unsigned short*)allocF(640000);
  unsigned short* k_w_h = (unsigned short*)allocF(2560000);
  unsigned short* v_w_h = (unsigned short*)allocF(2560000);
  unsigned short* k_t_h = (unsigned short*)allocF(256000);
  unsigned short* v_t_h = (unsigned short*)allocF(256000);
  unsigned short* khat0 = (unsigned short*)allocF(2560000);
  unsigned short* khat1 = (unsigned short*)allocF(2560000);
  unsigned short* khat2 = (unsigned short*)allocF(2560000);
  unsigned short* khat3 = (unsigned short*)allocF(256000);
  unsigned short* khat4 = (unsigned short*)allocF(256000);
  unsigned short* vhat0 = (unsigned short*)allocF(2560000);
  unsigned short* vhat1 = (unsigned short*)allocF(2560000);
  unsigned short* vhat2 = (unsigned short*)allocF(2560000);
  unsigned short* vhat3 = (unsigned short*)allocF(256000);
  unsigned short* vhat4 = (unsigned short*)allocF(256000);
  float* agg_ww = allocF(5120000);
  float* agg_wt = allocF(512000);
  float* agg_wd = allocF(1280000);
  float* agg_tt = allocF(512000);
  float* agg_td = allocF(1280000);
  unsigned short* WTw = (unsigned short*)allocF(98304);
  unsigned short* WTt = (unsigned short*)allocF(98304);
  unsigned short* WTd = (unsigned short*)allocF(32768);
  unsigned short* WTa = (unsigned short*)allocF(98304);
  unsigned short* wkp = (unsigned short*)allocF(20480);
  unsigned short* wvp = (unsigned short*)allocF(20480);
  int* counts  = (int*)allocF(34000);
  int* cursor  = (int*)allocF(34000);
  int* offsets = (int*)allocF(34008);
  int* ssrc    = (int*)allocF(370000);

  dim3 b256(256);
  auto cdiv = [](int a, int b) { return (a + b - 1) / b; };

  Pack10 p10;
  p10.src[0] = Wq;          p10.dst[0] = WTw;
  p10.src[1] = Wk;          p10.dst[1] = WTw + 65536;
  p10.src[2] = Wv;          p10.dst[2] = WTw + 131072;
  p10.src[3] = Wq + 65536;  p10.dst[3] = WTt;
  p10.src[4] = Wk + 65536;  p10.dst[4] = WTt + 65536;
  p10.src[5] = Wv + 65536;  p10.dst[5] = WTt + 131072;
  p10.src[6] = Wq + 131072; p10.dst[6] = WTd;
  p10.src[7] = Wa;          p10.dst[7] = WTa;
  p10.src[8] = Wa + 65536;  p10.dst[8] = WTa + 65536;
  p10.src[9] = Wa + 131072; p10.dst[9] = WTa + 131072;
  pack_wt10<<<dim3(10, 8, 8), b256, 0, stream>>>(p10);
  pack_headw<<<160, b256, 0, stream>>>(rel_att, wkp, 5);
  pack_headw<<<160, b256, 0, stream>>>(rel_msg, wvp, 5);

  CsrDesc dsc;
  dsc.dst[0] = dst_ww; dsc.dst[1] = dst_wt; dsc.dst[2] = dst_wd; dsc.dst[3] = dst_tt; dsc.dst[4] = dst_td;
  dsc.src[0] = src_ww; dsc.src[1] = src_wt; dsc.src[2] = src_wd; dsc.src[3] = src_tt; dsc.src[4] = src_td;
  int Es[5] = {E_WW, E_WT, E_WD, E_TT, E_TD};
  int Ns[5] = {NW, NT, ND, NT, ND};
  int cb = 0, eb = 0;
  for (int r = 0; r < 5; r++) {
    dsc.E[r] = Es[r]; dsc.N[r] = Ns[r];
    dsc.cbase[r] = cb; dsc.obase[r] = cb + r; dsc.ebase[r] = eb;
    cb += Ns[r]; eb += Es[r];
  }
  hipMemsetAsync(counts, 0, (size_t)68000 * sizeof(int), stream);
  hist5<<<cdiv(370000, 256), b256, 0, stream>>>(dsc, counts);
  scan5<<<5, 1024, 0, stream>>>(counts, offsets, dsc);
  scatter5<<<cdiv(370000, 256), b256, 0, stream>>>(dsc, offsets, cursor, ssrc);

  {
    ProjArgs pw; pw.A = feat_w; pw.WT = WTw; pw.M = NW;
    pw.bias[0] = bq; pw.bias[1] = bk; pw.bias[2] = bv;
    pw.outp[0] = q_w_h; pw.outp[1] = k_w_h; pw.outp[2] = v_w_h;
    proj_gemm<<<dim3(cdiv(NW, 64), 12), b256, 0, stream>>>(pw);
    ProjArgs pt; pt.A = feat_t; pt.WT = WTt; pt.M = NT;
    pt.bias[0] = bq + 256; pt.bias[1] = bk + 256; pt.bias[2] = bv + 256;
    pt.outp[0] = q_t_h; pt.outp[1] = k_t_h; pt.outp[2] = v_t_h;
    proj_gemm<<<dim3(cdiv(NT, 64), 12), b256, 0, stream>>>(pt);
    ProjArgs pd; pd.A = feat_d; pd.WT = WTd; pd.M = ND;
    pd.bias[0] = bq + 512; pd.bias[1] = bq + 512; pd.bias[2] = bq + 512;
    pd.outp[0] = q_d_h; pd.outp[1] = q_d_h; pd.outp[2] = q_d_h;
    proj_gemm<<<dim3(cdiv(ND, 64), 4), b256, 0, stream>>>(pd);
  }

  {
    HtArgs ha;
    ha.kin[0] = ha.kin[1] = ha.kin[2] = k_w_h; ha.kin[3] = ha.kin[4] = k_t_h;
    ha.vin[0] = ha.vin[1] = ha.vin[2] = v_w_h; ha.vin[3] = ha.vin[4] = v_t_h;
    ha.khat[0] = khat0; ha.khat[1] = khat1; ha.khat[2] = khat2; ha.khat[3] = khat3; ha.khat[4] = khat4;
    ha.vhat[0] = vhat0; ha.vhat[1] = vhat1; ha.vhat[2] = vhat2; ha.vhat[3] = vhat3; ha.vhat[4] = vhat4;
    ha.wk = wkp; ha.wv = wvp;
    int bc = 0;
    for (int r = 0; r < 5; r++) {
      int Nsrc = (r < 3) ? NW : NT;
      ha.N[r] = Nsrc; ha.bcum[r] = bc; bc += cdiv(Nsrc, 64);
    }
    ha.bcum[5] = bc;
    head_transform_all<<<bc, b256, 0, stream>>>(ha);
  }

  {
    AttArgs aa;
    aa.q[0] = q_w_h; aa.q[1] = q_t_h; aa.q[2] = q_d_h; aa.q[3] = q_t_h; aa.q[4] = q_d_h;
    aa.kh[0] = khat0; aa.kh[1] = khat1; aa.kh[2] = khat2; aa.kh[3] = khat3; aa.kh[4] = khat4;
    aa.vh[0] = vhat0; aa.vh[1] = vhat1; aa.vh[2] = vhat2; aa.vh[3] = vhat3; aa.vh[4] = vhat4;
    float* aggs[5] = {agg_ww, agg_wt, agg_wd, agg_tt, agg_td};
    int NdstA[5] = {NW, NT, ND, NT, ND};
    int bc = 0;
    for (int r = 0; r < 5; r++) {
      aa.ssrc[r] = ssrc + dsc.ebase[r];
      aa.offs[r] = offsets + dsc.obase[r];
      aa.agg[r] = aggs[r];
      aa.Ndst[r] = NdstA[r];
      aa.bcum[r] = bc; bc += cdiv(NdstA[r], 4);
    }
    aa.bcum[5] = bc;
    aa.pri = rel_pri;
    fused_att_agg<<<bc, b256, 0, stream>>>(aa);
  }

  out_gemm_ln<<<cdiv(NW, 64), b256, 0, stream>>>(
      agg_ww, nullptr, 1.0f, WTa, ba, feat_w, skip, 0, ln_scale, ln_bias, out, NW);
  out_gemm_ln<<<cdiv(NT, 64), b256, 0, stream>>>(
      agg_wt, agg_tt, 0.5f, WTa + 65536, ba + 256, feat_t, skip, 1,
      ln_scale + 256, ln_bias + 256, out + (size_t)NW * 256, NT);
  out_gemm_ln<<<cdiv(ND, 64), b256, 0, stream>>>(
      agg_wd, agg_td, 0.5f, WTa + 131072, ba + 512, feat_d, skip, 2,
      ln_scale + 512, ln_bias + 512, out + (size_t)(NW + NT) * 256, ND);

  (void)in_sizes; (void)n_in; (void)out_size; (void)ws_size;
}

// Round 7
// 292.819 us; speedup vs baseline: 6.7950x; 1.1282x over previous
//
#include <hip/hip_runtime.h>

static constexpr int NW = 20000, NT = 2000, ND = 5000;
static constexpr int E_WW = 150000, E_WT = 80000, E_WD = 80000, E_TT = 20000, E_TD = 40000;

typedef short bf16x8 __attribute__((ext_vector_type(8)));
typedef float f32x4 __attribute__((ext_vector_type(4)));

__device__ __forceinline__ unsigned short f2bf(float f) {
  union { float f; unsigned int u; } c; c.f = f;
  unsigned int u = c.u;
  u += 0x7fffu + ((u >> 16) & 1u);
  return (unsigned short)(u >> 16);
}
__device__ __forceinline__ float bf2f(unsigned short h) {
  union { unsigned int u; float f; } c; c.u = ((unsigned int)h) << 16; return c.f;
}
__device__ __forceinline__ bf16x8 pack8(float4 a, float4 b) {
  bf16x8 r;
  r[0] = (short)f2bf(a.x); r[1] = (short)f2bf(a.y); r[2] = (short)f2bf(a.z); r[3] = (short)f2bf(a.w);
  r[4] = (short)f2bf(b.x); r[5] = (short)f2bf(b.y); r[6] = (short)f2bf(b.z); r[7] = (short)f2bf(b.w);
  return r;
}

// ---------------- pack 10 weight matrices: W[k][n] f32 -> WT[n][k] bf16 ----------------
struct Pack10 { const float* src[10]; unsigned short* dst[10]; };
__global__ __launch_bounds__(256) void pack_wt10(Pack10 p) {
  __shared__ float tile[32][33];
  const float* W = p.src[blockIdx.x];
  unsigned short* WT = p.dst[blockIdx.x];
  int bk = blockIdx.y * 32, bn = blockIdx.z * 32;
  int tx = threadIdx.x & 31, ty = threadIdx.x >> 5;
#pragma unroll
  for (int i = 0; i < 32; i += 8)
    tile[ty + i][tx] = W[(size_t)(bk + ty + i) * 256 + bn + tx];
  __syncthreads();
#pragma unroll
  for (int i = 0; i < 32; i += 8)
    WT[(size_t)(bn + ty + i) * 256 + bk + tx] = f2bf(tile[tx][ty + i]);
}

// ---------------- rel head weights -> MFMA B-frag order bf16 ----------------
// SWAP=0: B[k][n] = w[h][k][n]  (msg side: out = in @ W)
// SWAP=1: B[k][n] = w[h][n][k]  (att side: qhat = q @ W^T)
template <int SWAP>
__global__ void pack_headw(const float* __restrict__ w, unsigned short* __restrict__ out, int nmat) {
  int t = blockIdx.x * blockDim.x + threadIdx.x;
  if (t >= nmat * 8192) return;
  int m = t >> 13, rem = t & 8191;
  int hc = rem >> 9, idx = rem & 511;
  int lane = idx >> 3, j = idx & 7;
  int h = hc >> 1, c = hc & 1;
  int k = (lane >> 4) * 8 + j, n = c * 16 + (lane & 15);
  int srcIdx = SWAP ? (n * 32 + k) : (k * 32 + n);
  out[t] = f2bf(w[(size_t)m * 8192 + h * 1024 + srcIdx]);
}

// ---------------- wide projection GEMM: out[seg] = A(f32) @ WT_seg + b_seg, bf16 out ----
struct ProjArgs {
  const float* A; const unsigned short* WT;
  const float* bias[3]; unsigned short* outp[3];
  int M;
};
__global__ __launch_bounds__(256) void proj_gemm(ProjArgs pa) {
  __shared__ unsigned short As[64 * 64];
  __shared__ unsigned short Bs[64 * 64];
  const int bm = blockIdx.x * 64, bn = blockIdx.y * 64;
  const int seg = blockIdx.y >> 2;
  const int tid = threadIdx.x, wave = tid >> 6, lane = tid & 63;
  f32x4 acc[4] = {};
  const int ar = wave * 16 + (lane & 15);
  const int swz = lane & 7;
  for (int k0 = 0; k0 < 256; k0 += 64) {
#pragma unroll
    for (int i = 0; i < 2; i++) {
      int c = tid + i * 256;
      int row = c >> 3, sl = c & 7;
      int srow = bm + row;
      float4 a0 = make_float4(0.f, 0.f, 0.f, 0.f), a1 = a0;
      if (srow < pa.M) {
        a0 = *(const float4*)(pa.A + (size_t)srow * 256 + k0 + sl * 8);
        a1 = *(const float4*)(pa.A + (size_t)srow * 256 + k0 + sl * 8 + 4);
      }
      *(bf16x8*)&As[row * 64 + (sl ^ (row & 7)) * 8] = pack8(a0, a1);
      bf16x8 bv = *(const bf16x8*)(pa.WT + (size_t)(bn + row) * 256 + k0 + sl * 8);
      *(bf16x8*)&Bs[row * 64 + (sl ^ (row & 7)) * 8] = bv;
    }
    __syncthreads();
#pragma unroll
    for (int kk = 0; kk < 2; kk++) {
      int slot = kk * 4 + (lane >> 4);
      bf16x8 a = *(const bf16x8*)&As[ar * 64 + ((slot ^ swz) * 8)];
#pragma unroll
      for (int nf = 0; nf < 4; nf++) {
        int br = nf * 16 + (lane & 15);
        bf16x8 b = *(const bf16x8*)&Bs[br * 64 + ((slot ^ swz) * 8)];
        acc[nf] = __builtin_amdgcn_mfma_f32_16x16x32_bf16(a, b, acc[nf], 0, 0, 0);
      }
    }
    __syncthreads();
  }
  const int col = lane & 15;
  const float* bias = pa.bias[seg];
  unsigned short* outp = pa.outp[seg];
  const int cbk = bn & 255;
#pragma unroll
  for (int nf = 0; nf < 4; nf++) {
    float bsv = bias[cbk + nf * 16 + col];
#pragma unroll
    for (int rr = 0; rr < 4; rr++) {
      int row = bm + wave * 16 + (lane >> 4) * 4 + rr;
      if (row < pa.M)
        outp[(size_t)row * 256 + cbk + nf * 16 + col] = f2bf(acc[nf][rr] + bsv);
    }
  }
}

// ---------------- qhat = per-head q @ att_w^T, all 5 rels in one dispatch ----------------
struct QhArgs {
  const unsigned short* qin[5];
  unsigned short* qh[5];
  const unsigned short* wq;  // SWAP-packed, 5 * 8192
  int N[5]; int bcum[6];
};
__global__ __launch_bounds__(256) void qhat_transform_all(QhArgs a) {
  int r = 0;
  while (r < 4 && (int)blockIdx.x >= a.bcum[r + 1]) r++;
  int local = blockIdx.x - a.bcum[r];
  const unsigned short* qin = a.qin[r];
  unsigned short* qh = a.qh[r];
  const unsigned short* wf = a.wq + (size_t)r * 8192;
  int N = a.N[r];
  int wave = threadIdx.x >> 6, lane = threadIdx.x & 63;
  int r0 = local * 64 + wave * 16;
  int arow = r0 + (lane & 15);
  bool valid = arow < N;
  int kofs = (lane >> 4) * 8;
  f32x4 z{};
#pragma unroll
  for (int h = 0; h < 8; h++) {
    bf16x8 aq{};
    if (valid) aq = *(const bf16x8*)(qin + (size_t)arow * 256 + h * 32 + kofs);
#pragma unroll
    for (int c = 0; c < 2; c++) {
      bf16x8 b = *(const bf16x8*)(wf + ((h * 2 + c) * 64 + lane) * 8);
      f32x4 o = __builtin_amdgcn_mfma_f32_16x16x32_bf16(aq, b, z, 0, 0, 0);
      int colc = h * 32 + c * 16 + (lane & 15);
#pragma unroll
      for (int rr = 0; rr < 4; rr++) {
        int row = r0 + (lane >> 4) * 4 + rr;
        if (row < N) qh[(size_t)row * 256 + colc] = f2bf(o[rr]);
      }
    }
  }
}

// ---------------- fused CSR build over all 5 relations ----------------
struct CsrDesc {
  const int* dst[5];
  const int* src[5];
  int E[5], N[5], cbase[5], obase[5], ebase[5];
};

__global__ void hist5(CsrDesc d, int* __restrict__ counts) {
  int t = blockIdx.x * blockDim.x + threadIdx.x;
  int r = 0, base = 0;
  while (r < 5 && t >= base + d.E[r]) { base += d.E[r]; r++; }
  if (r >= 5) return;
  int e = t - base;
  atomicAdd(counts + d.cbase[r] + d.dst[r][e], 1);
}

__global__ __launch_bounds__(1024) void scan5(const int* __restrict__ counts,
                                              int* __restrict__ offsets, CsrDesc d) {
  int r = blockIdx.x;
  int N = d.N[r];
  const int* cnt = counts + d.cbase[r];
  int* off = offsets + d.obase[r];
  __shared__ int wtot[16];
  __shared__ int carry_s;
  int tid = threadIdx.x, lane = tid & 63, w = tid >> 6;
  if (tid == 0) carry_s = 0;
  __syncthreads();
  for (int base = 0; base < N; base += 1024) {
    int i = base + tid;
    int v = (i < N) ? cnt[i] : 0;
    int x = v;
#pragma unroll
    for (int dlt = 1; dlt < 64; dlt <<= 1) {
      int t = __shfl_up(x, dlt, 64);
      if (lane >= dlt) x += t;
    }
    if (lane == 63) wtot[w] = x;
    __syncthreads();
    if (w == 0) {
      int y = (lane < 16) ? wtot[lane] : 0;
#pragma unroll
      for (int dlt = 1; dlt < 16; dlt <<= 1) {
        int t = __shfl_up(y, dlt, 64);
        if (lane >= dlt) y += t;
      }
      if (lane < 16) wtot[lane] = y;
    }
    __syncthreads();
    int wpre = (w > 0) ? wtot[w - 1] : 0;
    int incl = carry_s + wpre + x;
    if (i < N) off[i] = incl - v;
    __syncthreads();
    if (tid == 1023) carry_s = incl;
    __syncthreads();
  }
  if (threadIdx.x == 0) off[N] = carry_s;
}

__global__ void scatter5(CsrDesc d, const int* __restrict__ offsets, int* __restrict__ cursor,
                         int* __restrict__ ssrc) {
  int t = blockIdx.x * blockDim.x + threadIdx.x;
  int r = 0, base = 0;
  while (r < 5 && t >= base + d.E[r]) { base += d.E[r]; r++; }
  if (r >= 5) return;
  int e = t - base;
  int dn = d.dst[r][e];
  int pos = offsets[d.obase[r] + dn] + atomicAdd(cursor + d.cbase[r] + dn, 1);
  ssrc[d.ebase[r] + pos] = d.src[r][e];
}

// ---------------- fused edge attention + online softmax + raw-V aggregation ----------
struct AttArgs {
  const unsigned short* qh[5]; const unsigned short* kraw[5]; const unsigned short* vraw[5];
  const int* ssrc[5]; const int* offs[5]; unsigned short* agg[5];
  const float* pri;
  int bcum[6]; int Ndst[5];
};
__global__ __launch_bounds__(256) void fused_att_agg(AttArgs a) {
  int r = 0;
  while (r < 4 && (int)blockIdx.x >= a.bcum[r + 1]) r++;
  int wave = threadIdx.x >> 6, lane = threadIdx.x & 63;
  int node = (blockIdx.x - a.bcum[r]) * 4 + wave;
  if (node >= a.Ndst[r]) return;
  const unsigned short* qh = a.qh[r];
  const unsigned short* kh = a.kraw[r];
  const unsigned short* vh = a.vraw[r];
  const int* ssrc = a.ssrc[r];
  const int* offs = a.offs[r];
  int h = lane >> 3;
  float prih = a.pri[r * 8 + h] * 0.17677669529663687f;  // pri/sqrt(32)
  int r0 = offs[node], r1 = offs[node + 1];
  float4 acc = make_float4(0.f, 0.f, 0.f, 0.f);
  if (r0 < r1) {
    ushort4 qv = *(const ushort4*)(qh + (size_t)node * 256 + lane * 4);
    float q0 = bf2f(qv.x), q1 = bf2f(qv.y), q2 = bf2f(qv.z), q3 = bf2f(qv.w);
    float m = -1e30f, s = 0.f;
    int sn = ssrc[r0];
    ushort4 kv = *(const ushort4*)(kh + (size_t)sn * 256 + lane * 4);
    ushort4 vv = *(const ushort4*)(vh + (size_t)sn * 256 + lane * 4);
    for (int i = r0; i < r1; i++) {
      ushort4 kn = kv, vn = vv;
      if (i + 1 < r1) {
        int s2 = ssrc[i + 1];
        kn = *(const ushort4*)(kh + (size_t)s2 * 256 + lane * 4);
        vn = *(const ushort4*)(vh + (size_t)s2 * 256 + lane * 4);
      }
      float d = q0 * bf2f(kv.x) + q1 * bf2f(kv.y) + q2 * bf2f(kv.z) + q3 * bf2f(kv.w);
      d += __shfl_xor(d, 1, 64);
      d += __shfl_xor(d, 2, 64);
      d += __shfl_xor(d, 4, 64);
      float logit = d * prih;
      float mn = fmaxf(m, logit);
      float scale = __expf(m - mn);
      float w = __expf(logit - mn);
      m = mn;
      s = s * scale + w;
      acc.x = acc.x * scale + w * bf2f(vv.x);
      acc.y = acc.y * scale + w * bf2f(vv.y);
      acc.z = acc.z * scale + w * bf2f(vv.z);
      acc.w = acc.w * scale + w * bf2f(vv.w);
      kv = kn; vv = vn;   // rotate prefetch (round-6 bug: this was missing)
    }
    float inv = 1.f / fmaxf(s, 1e-9f);
    acc.x *= inv; acc.y *= inv; acc.z *= inv; acc.w *= inv;
  }
  ushort4 o;
  o.x = f2bf(acc.x); o.y = f2bf(acc.y); o.z = f2bf(acc.z); o.w = f2bf(acc.w);
  *(ushort4*)(a.agg[r] + (size_t)node * 256 + lane * 4) = o;
}

// ---------------- msg transform on aggregates + relu + cross-etype mean -> t bf16 ------
struct MsgArgs {
  const unsigned short* aggA[3]; const unsigned short* aggB[3];
  const unsigned short* fA[3]; const unsigned short* fB[3];
  unsigned short* t[3];
  float scale[3];
  int N[3]; int bcum[4];
};
__global__ __launch_bounds__(256) void msg_transform_all(MsgArgs a) {
  int g = 0;
  while (g < 2 && (int)blockIdx.x >= a.bcum[g + 1]) g++;
  int local = blockIdx.x - a.bcum[g];
  const unsigned short* aggA = a.aggA[g];
  const unsigned short* aggB = a.aggB[g];
  const unsigned short* fA = a.fA[g];
  const unsigned short* fB = a.fB[g];
  unsigned short* t = a.t[g];
  float scale = a.scale[g];
  int N = a.N[g];
  int wave = threadIdx.x >> 6, lane = threadIdx.x & 63;
  int r0 = local * 64 + wave * 16;
  int arow = r0 + (lane & 15);
  bool valid = arow < N;
  int kofs = (lane >> 4) * 8;
  f32x4 z{};
#pragma unroll
  for (int h = 0; h < 8; h++) {
    bf16x8 aA{}, aB{};
    if (valid) {
      aA = *(const bf16x8*)(aggA + (size_t)arow * 256 + h * 32 + kofs);
      if (aggB) aB = *(const bf16x8*)(aggB + (size_t)arow * 256 + h * 32 + kofs);
    }
#pragma unroll
    for (int c = 0; c < 2; c++) {
      bf16x8 bA = *(const bf16x8*)(fA + ((h * 2 + c) * 64 + lane) * 8);
      f32x4 oA = __builtin_amdgcn_mfma_f32_16x16x32_bf16(aA, bA, z, 0, 0, 0);
      f32x4 oB = z;
      if (aggB) {
        bf16x8 bB = *(const bf16x8*)(fB + ((h * 2 + c) * 64 + lane) * 8);
        oB = __builtin_amdgcn_mfma_f32_16x16x32_bf16(aB, bB, z, 0, 0, 0);
      }
      int colc = h * 32 + c * 16 + (lane & 15);
#pragma unroll
      for (int rr = 0; rr < 4; rr++) {
        int row = r0 + (lane >> 4) * 4 + rr;
        if (row < N) {
          float v = fmaxf(oA[rr], 0.f) + fmaxf(oB[rr], 0.f);
          t[(size_t)row * 256 + colc] = f2bf(v * scale);
        }
      }
    }
  }
}

// ---------------- output GEMM (A = t bf16) + skip-blend + LayerNorm ------
__global__ __launch_bounds__(256) void out_gemm_ln(
    const unsigned short* __restrict__ tA,
    const unsigned short* __restrict__ WT, const float* __restrict__ ba,
    const float* __restrict__ feat, const float* __restrict__ skipv, int skipIdx,
    const float* __restrict__ gamma, const float* __restrict__ beta,
    float* __restrict__ out, int M) {
  __shared__ unsigned short As[64 * 64];
  __shared__ unsigned short Bs[256 * 64];
  const int bm = blockIdx.x * 64;
  const int tid = threadIdx.x, wave = tid >> 6, lane = tid & 63;
  f32x4 acc[16] = {};
  const int ar = wave * 16 + (lane & 15);
  const int swz = lane & 7;
  for (int k0 = 0; k0 < 256; k0 += 64) {
#pragma unroll
    for (int i = 0; i < 2; i++) {
      int c = tid + i * 256;
      int row = c >> 3, sl = c & 7;
      int srow = bm + row;
      bf16x8 av{};
      if (srow < M) av = *(const bf16x8*)(tA + (size_t)srow * 256 + k0 + sl * 8);
      *(bf16x8*)&As[row * 64 + (sl ^ (row & 7)) * 8] = av;
    }
#pragma unroll
    for (int i = 0; i < 8; i++) {
      int c = tid + i * 256;
      int row = c >> 3, sl = c & 7;
      bf16x8 bv = *(const bf16x8*)(WT + (size_t)row * 256 + k0 + sl * 8);
      *(bf16x8*)&Bs[row * 64 + (sl ^ (row & 7)) * 8] = bv;
    }
    __syncthreads();
#pragma unroll
    for (int kk = 0; kk < 2; kk++) {
      int slot = kk * 4 + (lane >> 4);
      bf16x8 a = *(const bf16x8*)&As[ar * 64 + ((slot ^ swz) * 8)];
#pragma unroll
      for (int nf = 0; nf < 16; nf++) {
        int br = nf * 16 + (lane & 15);
        bf16x8 b = *(const bf16x8*)&Bs[br * 64 + ((slot ^ swz) * 8)];
        acc[nf] = __builtin_amdgcn_mfma_f32_16x16x32_bf16(a, b, acc[nf], 0, 0, 0);
      }
    }
    __syncthreads();
  }
  const int c16 = lane & 15;
  float a_skip = 1.f / (1.f + __expf(-skipv[skipIdx]));
  float one_m = 1.f - a_skip;
  float g[16], bb[16], bia[16];
#pragma unroll
  for (int nf = 0; nf < 16; nf++) {
    g[nf] = gamma[nf * 16 + c16];
    bb[nf] = beta[nf * 16 + c16];
    bia[nf] = ba[nf * 16 + c16];
  }
#pragma unroll
  for (int rr = 0; rr < 4; rr++) {
    int row = bm + wave * 16 + (lane >> 4) * 4 + rr;
    bool valid = row < M;
#pragma unroll
    for (int nf = 0; nf < 16; nf++) {
      float fv = valid ? feat[(size_t)row * 256 + nf * 16 + c16] : 0.f;
      acc[nf][rr] = (acc[nf][rr] + bia[nf]) * a_skip + fv * one_m;
    }
    float p = 0.f;
#pragma unroll
    for (int nf = 0; nf < 16; nf++) p += acc[nf][rr];
    p += __shfl_xor(p, 1, 16); p += __shfl_xor(p, 2, 16);
    p += __shfl_xor(p, 4, 16); p += __shfl_xor(p, 8, 16);
    float mu = p * (1.f / 256.f);
    float qv = 0.f;
#pragma unroll
    for (int nf = 0; nf < 16; nf++) { float dd = acc[nf][rr] - mu; qv += dd * dd; }
    qv += __shfl_xor(qv, 1, 16); qv += __shfl_xor(qv, 2, 16);
    qv += __shfl_xor(qv, 4, 16); qv += __shfl_xor(qv, 8, 16);
    float rstd = rsqrtf(qv * (1.f / 256.f) + 1e-5f);
    if (valid) {
#pragma unroll
      for (int nf = 0; nf < 16; nf++)
        out[(size_t)row * 256 + nf * 16 + c16] = (acc[nf][rr] - mu) * rstd * g[nf] + bb[nf];
    }
  }
}

extern "C" void kernel_launch(void* const* d_in, const int* in_sizes, int n_in,
                              void* d_out, int out_size, void* d_ws, size_t ws_size,
                              hipStream_t stream) {
  const float* feat_w = (const float*)d_in[0];
  const float* feat_t = (const float*)d_in[1];
  const float* feat_d = (const float*)d_in[2];
  const float* Wk = (const float*)d_in[3];
  const float* bk = (const float*)d_in[4];
  const float* Wq = (const float*)d_in[5];
  const float* bq = (const float*)d_in[6];
  const float* Wv = (const float*)d_in[7];
  const float* bv = (const float*)d_in[8];
  const float* Wa = (const float*)d_in[9];
  const float* ba = (const float*)d_in[10];
  const float* ln_scale = (const float*)d_in[11];
  const float* ln_bias = (const float*)d_in[12];
  const float* skip = (const float*)d_in[13];
  const float* rel_pri = (const float*)d_in[14];
  const float* rel_att = (const float*)d_in[15];
  const float* rel_msg = (const float*)d_in[16];
  const int* src_ww = (const int*)d_in[17];
  const int* dst_ww = (const int*)d_in[18];
  const int* src_wt = (const int*)d_in[19];
  const int* dst_wt = (const int*)d_in[20];
  const int* src_wd = (const int*)d_in[21];
  const int* dst_wd = (const int*)d_in[22];
  const int* src_tt = (const int*)d_in[23];
  const int* dst_tt = (const int*)d_in[24];
  const int* src_td = (const int*)d_in[25];
  const int* dst_td = (const int*)d_in[26];
  float* out = (float*)d_out;
  float* ws = (float*)d_ws;

  // ---- workspace (sizes in FLOAT units; bf16 buf of N elems = N/2 floats) ----
  size_t off = 0;
  auto allocF = [&](size_t nf) { float* p = ws + off; off += nf; return p; };
  unsigned short* q_w_h = (unsigned short*)allocF(2560000);
  unsigned short* q_t_h = (unsigned short*)allocF(256000);
  unsigned short* q_d_h = (unsigned short*)allocF(640000);
  unsigned short* k_w_h = (unsigned short*)allocF(2560000);
  unsigned short* v_w_h = (unsigned short*)allocF(2560000);
  unsigned short* k_t_h = (unsigned short*)allocF(256000);
  unsigned short* v_t_h = (unsigned short*)allocF(256000);
  unsigned short* qhat0 = (unsigned short*)allocF(2560000);
  unsigned short* qhat1 = (unsigned short*)allocF(256000);
  unsigned short* qhat2 = (unsigned short*)allocF(640000);
  unsigned short* qhat3 = (unsigned short*)allocF(256000);
  unsigned short* qhat4 = (unsigned short*)allocF(640000);
  unsigned short* aggr0 = (unsigned short*)allocF(2560000);
  unsigned short* aggr1 = (unsigned short*)allocF(256000);
  unsigned short* aggr2 = (unsigned short*)allocF(640000);
  unsigned short* aggr3 = (unsigned short*)allocF(256000);
  unsigned short* aggr4 = (unsigned short*)allocF(640000);
  unsigned short* t_word  = (unsigned short*)allocF(2560000);
  unsigned short* t_topic = (unsigned short*)allocF(256000);
  unsigned short* t_doc   = (unsigned short*)allocF(640000);
  unsigned short* WTw = (unsigned short*)allocF(98304);
  unsigned short* WTt = (unsigned short*)allocF(98304);
  unsigned short* WTd = (unsigned short*)allocF(32768);
  unsigned short* WTa = (unsigned short*)allocF(98304);
  unsigned short* wap = (unsigned short*)allocF(20480);  // att side, SWAP=1
  unsigned short* wvp = (unsigned short*)allocF(20480);  // msg side, SWAP=0
  int* counts  = (int*)allocF(34000);
  int* cursor  = (int*)allocF(34000);
  int* offsets = (int*)allocF(34008);
  int* ssrc    = (int*)allocF(370000);

  dim3 b256(256);
  auto cdiv = [](int a, int b) { return (a + b - 1) / b; };

  // ---- weight packing ----
  Pack10 p10;
  p10.src[0] = Wq;          p10.dst[0] = WTw;
  p10.src[1] = Wk;          p10.dst[1] = WTw + 65536;
  p10.src[2] = Wv;          p10.dst[2] = WTw + 131072;
  p10.src[3] = Wq + 65536;  p10.dst[3] = WTt;
  p10.src[4] = Wk + 65536;  p10.dst[4] = WTt + 65536;
  p10.src[5] = Wv + 65536;  p10.dst[5] = WTt + 131072;
  p10.src[6] = Wq + 131072; p10.dst[6] = WTd;
  p10.src[7] = Wa;          p10.dst[7] = WTa;
  p10.src[8] = Wa + 65536;  p10.dst[8] = WTa + 65536;
  p10.src[9] = Wa + 131072; p10.dst[9] = WTa + 131072;
  pack_wt10<<<dim3(10, 8, 8), b256, 0, stream>>>(p10);
  pack_headw<1><<<160, b256, 0, stream>>>(rel_att, wap, 5);
  pack_headw<0><<<160, b256, 0, stream>>>(rel_msg, wvp, 5);

  // ---- CSR build ----
  CsrDesc dsc;
  dsc.dst[0] = dst_ww; dsc.dst[1] = dst_wt; dsc.dst[2] = dst_wd; dsc.dst[3] = dst_tt; dsc.dst[4] = dst_td;
  dsc.src[0] = src_ww; dsc.src[1] = src_wt; dsc.src[2] = src_wd; dsc.src[3] = src_tt; dsc.src[4] = src_td;
  int Es[5] = {E_WW, E_WT, E_WD, E_TT, E_TD};
  int Ns[5] = {NW, NT, ND, NT, ND};
  int cb = 0, eb = 0;
  for (int r = 0; r < 5; r++) {
    dsc.E[r] = Es[r]; dsc.N[r] = Ns[r];
    dsc.cbase[r] = cb; dsc.obase[r] = cb + r; dsc.ebase[r] = eb;
    cb += Ns[r]; eb += Es[r];
  }
  hipMemsetAsync(counts, 0, (size_t)68000 * sizeof(int), stream);
  hist5<<<cdiv(370000, 256), b256, 0, stream>>>(dsc, counts);
  scan5<<<5, 1024, 0, stream>>>(dsc.dst[0] ? counts : counts, offsets, dsc);
  scatter5<<<cdiv(370000, 256), b256, 0, stream>>>(dsc, offsets, cursor, ssrc);

  // ---- projections ----
  {
    ProjArgs pw; pw.A = feat_w; pw.WT = WTw; pw.M = NW;
    pw.bias[0] = bq; pw.bias[1] = bk; pw.bias[2] = bv;
    pw.outp[0] = q_w_h; pw.outp[1] = k_w_h; pw.outp[2] = v_w_h;
    proj_gemm<<<dim3(cdiv(NW, 64), 12), b256, 0, stream>>>(pw);
    ProjArgs pt; pt.A = feat_t; pt.WT = WTt; pt.M = NT;
    pt.bias[0] = bq + 256; pt.bias[1] = bk + 256; pt.bias[2] = bv + 256;
    pt.outp[0] = q_t_h; pt.outp[1] = k_t_h; pt.outp[2] = v_t_h;
    proj_gemm<<<dim3(cdiv(NT, 64), 12), b256, 0, stream>>>(pt);
    ProjArgs pd; pd.A = feat_d; pd.WT = WTd; pd.M = ND;
    pd.bias[0] = bq + 512; pd.bias[1] = bq + 512; pd.bias[2] = bq + 512;
    pd.outp[0] = q_d_h; pd.outp[1] = q_d_h; pd.outp[2] = q_d_h;
    proj_gemm<<<dim3(cdiv(ND, 64), 4), b256, 0, stream>>>(pd);
  }

  int NdstA[5] = {NW, NT, ND, NT, ND};

  // ---- qhat transforms ----
  {
    QhArgs qa;
    qa.qin[0] = q_w_h; qa.qin[1] = q_t_h; qa.qin[2] = q_d_h; qa.qin[3] = q_t_h; qa.qin[4] = q_d_h;
    qa.qh[0] = qhat0; qa.qh[1] = qhat1; qa.qh[2] = qhat2; qa.qh[3] = qhat3; qa.qh[4] = qhat4;
    qa.wq = wap;
    int bc = 0;
    for (int r = 0; r < 5; r++) { qa.N[r] = NdstA[r]; qa.bcum[r] = bc; bc += cdiv(NdstA[r], 64); }
    qa.bcum[5] = bc;
    qhat_transform_all<<<bc, b256, 0, stream>>>(qa);
  }

  // ---- fused attention + softmax + raw-V aggregation ----
  {
    AttArgs aa;
    aa.qh[0] = qhat0; aa.qh[1] = qhat1; aa.qh[2] = qhat2; aa.qh[3] = qhat3; aa.qh[4] = qhat4;
    aa.kraw[0] = aa.kraw[1] = aa.kraw[2] = k_w_h; aa.kraw[3] = aa.kraw[4] = k_t_h;
    aa.vraw[0] = aa.vraw[1] = aa.vraw[2] = v_w_h; aa.vraw[3] = aa.vraw[4] = v_t_h;
    unsigned short* aggs[5] = {aggr0, aggr1, aggr2, aggr3, aggr4};
    int bc = 0;
    for (int r = 0; r < 5; r++) {
      aa.ssrc[r] = ssrc + dsc.ebase[r];
      aa.offs[r] = offsets + dsc.obase[r];
      aa.agg[r] = aggs[r];
      aa.Ndst[r] = NdstA[r];
      aa.bcum[r] = bc; bc += cdiv(NdstA[r], 4);
    }
    aa.bcum[5] = bc;
    aa.pri = rel_pri;
    fused_att_agg<<<bc, b256, 0, stream>>>(aa);
  }

  // ---- msg transform + relu + cross-etype mean -> t (bf16) ----
  {
    MsgArgs ma;
    ma.aggA[0] = aggr0; ma.aggB[0] = nullptr;
    ma.fA[0] = wvp;             ma.fB[0] = wvp;
    ma.t[0] = t_word;  ma.scale[0] = 1.0f;  ma.N[0] = NW;
    ma.aggA[1] = aggr1; ma.aggB[1] = aggr3;
    ma.fA[1] = wvp + 8192;      ma.fB[1] = wvp + 3 * 8192;
    ma.t[1] = t_topic; ma.scale[1] = 0.5f;  ma.N[1] = NT;
    ma.aggA[2] = aggr2; ma.aggB[2] = aggr4;
    ma.fA[2] = wvp + 2 * 8192;  ma.fB[2] = wvp + 4 * 8192;
    ma.t[2] = t_doc;   ma.scale[2] = 0.5f;  ma.N[2] = ND;
    int bc = 0;
    for (int g = 0; g < 3; g++) { ma.bcum[g] = bc; bc += cdiv(ma.N[g], 64); }
    ma.bcum[3] = bc;
    msg_transform_all<<<bc, b256, 0, stream>>>(ma);
  }

  // ---- output GEMM + skip + LayerNorm ----
  out_gemm_ln<<<cdiv(NW, 64), b256, 0, stream>>>(
      t_word, WTa, ba, feat_w, skip, 0, ln_scale, ln_bias, out, NW);
  out_gemm_ln<<<cdiv(NT, 64), b256, 0, stream>>>(
      t_topic, WTa + 65536, ba + 256, feat_t, skip, 1,
      ln_scale + 256, ln_bias + 256, out + (size_t)NW * 256, NT);
  out_gemm_ln<<<cdiv(ND, 64), b256, 0, stream>>>(
      t_doc, WTa + 131072, ba + 512, feat_d, skip, 2,
      ln_scale + 512, ln_bias + 512, out + (size_t)(NW + NT) * 256, ND);

  (void)in_sizes; (void)n_in; (void)out_size; (void)ws_size;
}

// Round 8
// 228.565 us; speedup vs baseline: 8.7052x; 1.2811x over previous
//
#include <hip/hip_runtime.h>

static constexpr int NW = 20000, NT = 2000, ND = 5000;
static constexpr int E_WW = 150000, E_WT = 80000, E_WD = 80000, E_TT = 20000, E_TD = 40000;

typedef short bf16x8 __attribute__((ext_vector_type(8)));
typedef float f32x4 __attribute__((ext_vector_type(4)));

__device__ __forceinline__ unsigned short f2bf(float f) {
  union { float f; unsigned int u; } c; c.f = f;
  unsigned int u = c.u;
  u += 0x7fffu + ((u >> 16) & 1u);
  return (unsigned short)(u >> 16);
}
__device__ __forceinline__ float bf2f(unsigned short h) {
  union { unsigned int u; float f; } c; c.u = ((unsigned int)h) << 16; return c.f;
}
__device__ __forceinline__ bf16x8 pack8(float4 a, float4 b) {
  bf16x8 r;
  r[0] = (short)f2bf(a.x); r[1] = (short)f2bf(a.y); r[2] = (short)f2bf(a.z); r[3] = (short)f2bf(a.w);
  r[4] = (short)f2bf(b.x); r[5] = (short)f2bf(b.y); r[6] = (short)f2bf(b.z); r[7] = (short)f2bf(b.w);
  return r;
}

// ---------------- pack 7 weight matrices: W[k][n] f32 -> WT[n][k] bf16 ----------------
struct Pack7 { const float* src[7]; unsigned short* dst[7]; };
__global__ __launch_bounds__(256) void pack_wt7(Pack7 p) {
  __shared__ float tile[32][33];
  const float* W = p.src[blockIdx.x];
  unsigned short* WT = p.dst[blockIdx.x];
  int bk = blockIdx.y * 32, bn = blockIdx.z * 32;
  int tx = threadIdx.x & 31, ty = threadIdx.x >> 5;
#pragma unroll
  for (int i = 0; i < 32; i += 8)
    tile[ty + i][tx] = W[(size_t)(bk + ty + i) * 256 + bn + tx];
  __syncthreads();
#pragma unroll
  for (int i = 0; i < 32; i += 8)
    WT[(size_t)(bn + ty + i) * 256 + bk + tx] = f2bf(tile[tx][ty + i]);
}

// ---------------- msg head weights -> MFMA B-frag order bf16 (B[k][n]=w[h][k][n]) ------
__global__ void pack_headw(const float* __restrict__ w, unsigned short* __restrict__ out, int nmat) {
  int t = blockIdx.x * blockDim.x + threadIdx.x;
  if (t >= nmat * 8192) return;
  int m = t >> 13, rem = t & 8191;
  int hc = rem >> 9, idx = rem & 511;
  int lane = idx >> 3, j = idx & 7;
  int h = hc >> 1, c = hc & 1;
  int k = (lane >> 4) * 8 + j, n = c * 16 + (lane & 15);
  out[t] = f2bf(w[(size_t)m * 8192 + h * 1024 + k * 32 + n]);
}

// ---------------- effective q weights: WTe[r][n][kk] = sum_d Wq[kk][h*32+d]*att[r][h][j][d] ---
struct EffArgs {
  const float* wq[5]; const float* bq[5];
  unsigned short* dst[5];
  float* beff;          // 5*256 f32
  const float* att;
};
__global__ void wq_eff_kernel(EffArgs a) {
  int t = blockIdx.x * blockDim.x + threadIdx.x;
  if (t < 5 * 65536) {
    int r = t >> 16, rem = t & 65535;
    int n = rem >> 8, kk = rem & 255;
    int h = n >> 5, j = n & 31;
    const float* wrow = a.wq[r] + kk * 256 + h * 32;
    const float* arow = a.att + r * 8192 + h * 1024 + j * 32;
    float s = 0.f;
#pragma unroll
    for (int d = 0; d < 32; d += 4) {
      float4 wv = *(const float4*)(wrow + d);
      float4 av = *(const float4*)(arow + d);
      s += wv.x * av.x + wv.y * av.y + wv.z * av.z + wv.w * av.w;
    }
    a.dst[r][n * 256 + kk] = f2bf(s);
  } else {
    int idx = t - 5 * 65536;
    if (idx < 1280) {
      int r = idx >> 8, n = idx & 255;
      int h = n >> 5, j = n & 31;
      const float* brow = a.bq[r] + h * 32;
      const float* arow = a.att + r * 8192 + h * 1024 + j * 32;
      float s = 0.f;
#pragma unroll
      for (int d = 0; d < 32; d += 4) {
        float4 bv = *(const float4*)(brow + d);
        float4 av = *(const float4*)(arow + d);
        s += bv.x * av.x + bv.y * av.y + bv.z * av.z + bv.w * av.w;
      }
      a.beff[r * 256 + n] = s;
    }
  }
}

// ---------------- unified projection GEMM over 3 ntypes (all segments, 1 dispatch) -----
struct ProjAll {
  const float* A[3];
  const unsigned short* WT[3];
  const float* bias[3][4];
  unsigned short* outp[3][4];
  int ostride[3][4];
  int M[3], ncolb[3], bcum[4];
};
__global__ __launch_bounds__(256) void proj_all(ProjAll pa) {
  __shared__ unsigned short As[64 * 64];
  __shared__ unsigned short Bs[64 * 64];
  int nt = 0;
  while (nt < 2 && (int)blockIdx.x >= pa.bcum[nt + 1]) nt++;
  int local = blockIdx.x - pa.bcum[nt];
  int ncolb = pa.ncolb[nt];
  int bmi = local / ncolb, bnb = local % ncolb;
  const int bm = bmi * 64, bn = bnb * 64;
  const float* A = pa.A[nt];
  const unsigned short* WT = pa.WT[nt];
  const int M = pa.M[nt];
  const int tid = threadIdx.x, wave = tid >> 6, lane = tid & 63;
  f32x4 acc[4] = {};
  const int ar = wave * 16 + (lane & 15);
  const int swz = lane & 7;
  for (int k0 = 0; k0 < 256; k0 += 64) {
#pragma unroll
    for (int i = 0; i < 2; i++) {
      int c = tid + i * 256;
      int row = c >> 3, sl = c & 7;
      int srow = bm + row;
      float4 a0 = make_float4(0.f, 0.f, 0.f, 0.f), a1 = a0;
      if (srow < M) {
        a0 = *(const float4*)(A + (size_t)srow * 256 + k0 + sl * 8);
        a1 = *(const float4*)(A + (size_t)srow * 256 + k0 + sl * 8 + 4);
      }
      *(bf16x8*)&As[row * 64 + (sl ^ (row & 7)) * 8] = pack8(a0, a1);
      bf16x8 bv = *(const bf16x8*)(WT + (size_t)(bn + row) * 256 + k0 + sl * 8);
      *(bf16x8*)&Bs[row * 64 + (sl ^ (row & 7)) * 8] = bv;
    }
    __syncthreads();
#pragma unroll
    for (int kk = 0; kk < 2; kk++) {
      int slot = kk * 4 + (lane >> 4);
      bf16x8 a = *(const bf16x8*)&As[ar * 64 + ((slot ^ swz) * 8)];
#pragma unroll
      for (int nf = 0; nf < 4; nf++) {
        int br = nf * 16 + (lane & 15);
        bf16x8 b = *(const bf16x8*)&Bs[br * 64 + ((slot ^ swz) * 8)];
        acc[nf] = __builtin_amdgcn_mfma_f32_16x16x32_bf16(a, b, acc[nf], 0, 0, 0);
      }
    }
    __syncthreads();
  }
  const int col = lane & 15;
  const int seg = bnb >> 2;
  const float* bias = pa.bias[nt][seg];
  unsigned short* outp = pa.outp[nt][seg];
  const int ostride = pa.ostride[nt][seg];
  const int cbase = (bnb & 3) * 64;
#pragma unroll
  for (int nf = 0; nf < 4; nf++) {
    float bsv = bias[cbase + nf * 16 + col];
#pragma unroll
    for (int rr = 0; rr < 4; rr++) {
      int row = bm + wave * 16 + (lane >> 4) * 4 + rr;
      if (row < M)
        outp[(size_t)row * ostride + cbase + nf * 16 + col] = f2bf(acc[nf][rr] + bsv);
    }
  }
}

// ---------------- CSR build: hist / global scan / scatter ----------------
struct CsrDesc {
  const int* dst[5];
  const int* src[5];
  int E[5], N[5], cbase[5];
};

__global__ void hist5(CsrDesc d, int* __restrict__ counts) {
  int t = blockIdx.x * blockDim.x + threadIdx.x;
  int r = 0, base = 0;
  while (r < 5 && t >= base + d.E[r]) { base += d.E[r]; r++; }
  if (r >= 5) return;
  int e = t - base;
  atomicAdd(counts + d.cbase[r] + d.dst[r][e], 1);
}

__global__ __launch_bounds__(1024) void scan_all(const int* __restrict__ cnt,
                                                 int* __restrict__ off, int N) {
  __shared__ int wpart[16];
  __shared__ int carry_s;
  int tid = threadIdx.x, lane = tid & 63, w = tid >> 6;
  if (tid == 0) carry_s = 0;
  __syncthreads();
  for (int base = 0; base < N; base += 4096) {
    int idx = base + tid * 4;
    int v0 = 0, v1 = 0, v2 = 0, v3 = 0;
    if (idx + 3 < N) {
      int4 t4 = *(const int4*)(cnt + idx);
      v0 = t4.x; v1 = t4.y; v2 = t4.z; v3 = t4.w;
    } else if (idx < N) {
      v0 = cnt[idx];
      if (idx + 1 < N) v1 = cnt[idx + 1];
      if (idx + 2 < N) v2 = cnt[idx + 2];
    }
    int tsum = v0 + v1 + v2 + v3;
    int x = tsum;
#pragma unroll
    for (int dlt = 1; dlt < 64; dlt <<= 1) {
      int t = __shfl_up(x, dlt, 64);
      if (lane >= dlt) x += t;
    }
    if (lane == 63) wpart[w] = x;
    __syncthreads();
    if (w == 0 && lane < 16) {
      int y = wpart[lane];
#pragma unroll
      for (int dlt = 1; dlt < 16; dlt <<= 1) {
        int t = __shfl_up(y, dlt, 64);
        if (lane >= dlt) y += t;
      }
      wpart[lane] = y;
    }
    __syncthreads();
    int excl = carry_s + ((w > 0) ? wpart[w - 1] : 0) + (x - tsum);
    if (idx < N)     off[idx]     = excl;
    if (idx + 1 < N) off[idx + 1] = excl + v0;
    if (idx + 2 < N) off[idx + 2] = excl + v0 + v1;
    if (idx + 3 < N) off[idx + 3] = excl + v0 + v1 + v2;
    __syncthreads();
    if (tid == 1023) carry_s = excl + tsum;
    __syncthreads();
  }
  if (tid == 0) off[N] = carry_s;
}

__global__ void scatter5(CsrDesc d, const int* __restrict__ offsets, int* __restrict__ cursor,
                         int* __restrict__ ssrc) {
  int t = blockIdx.x * blockDim.x + threadIdx.x;
  int r = 0, base = 0;
  while (r < 5 && t >= base + d.E[r]) { base += d.E[r]; r++; }
  if (r >= 5) return;
  int e = t - base;
  int dn = d.dst[r][e];
  int pos = offsets[d.cbase[r] + dn] + atomicAdd(cursor + d.cbase[r] + dn, 1);
  ssrc[pos] = d.src[r][e];
}

// ---------------- fused edge attention + online softmax + raw-V aggregation ----------
// kv: interleaved [node][512] bf16 = k row | v row. 2-edge unrolled online softmax.
struct AttArgs {
  const unsigned short* qh[5]; const unsigned short* kv[5];
  const int* offs[5]; unsigned short* agg[5];
  const int* ssrc;
  const float* pri;
  int bcum[6]; int Ndst[5];
};
__global__ __launch_bounds__(256) void fused_att_agg(AttArgs a) {
  int r = 0;
  while (r < 4 && (int)blockIdx.x >= a.bcum[r + 1]) r++;
  int wave = threadIdx.x >> 6, lane = threadIdx.x & 63;
  int node = (blockIdx.x - a.bcum[r]) * 4 + wave;
  if (node >= a.Ndst[r]) return;
  const unsigned short* qh = a.qh[r];
  const unsigned short* kv = a.kv[r];
  const int* ssrc = a.ssrc;
  const int* offs = a.offs[r];
  int h = lane >> 3;
  float prih = a.pri[r * 8 + h] * 0.17677669529663687f;  // pri/sqrt(32)
  int r0 = offs[node], r1 = offs[node + 1];
  float4 acc = make_float4(0.f, 0.f, 0.f, 0.f);
  if (r0 < r1) {
    ushort4 qv = *(const ushort4*)(qh + (size_t)node * 256 + lane * 4);
    float q0 = bf2f(qv.x), q1 = bf2f(qv.y), q2 = bf2f(qv.z), q3 = bf2f(qv.w);
    float m = -1e30f, s = 0.f;
    for (int i = r0; i < r1; i += 2) {
      int sA = ssrc[i];
      bool two = (i + 1 < r1);
      int sB = two ? ssrc[i + 1] : sA;
      const unsigned short* pA = kv + (size_t)sA * 512 + lane * 4;
      const unsigned short* pB = kv + (size_t)sB * 512 + lane * 4;
      ushort4 kA = *(const ushort4*)pA;
      ushort4 kB = *(const ushort4*)pB;
      ushort4 vA = *(const ushort4*)(pA + 256);
      ushort4 vB = *(const ushort4*)(pB + 256);
      float dA = q0 * bf2f(kA.x) + q1 * bf2f(kA.y) + q2 * bf2f(kA.z) + q3 * bf2f(kA.w);
      float dB = q0 * bf2f(kB.x) + q1 * bf2f(kB.y) + q2 * bf2f(kB.z) + q3 * bf2f(kB.w);
      dA += __shfl_xor(dA, 1, 64); dB += __shfl_xor(dB, 1, 64);
      dA += __shfl_xor(dA, 2, 64); dB += __shfl_xor(dB, 2, 64);
      dA += __shfl_xor(dA, 4, 64); dB += __shfl_xor(dB, 4, 64);
      float lA = dA * prih;
      float lB = two ? dB * prih : -1e30f;
      float mn = fmaxf(m, fmaxf(lA, lB));
      float sc = __expf(m - mn);
      float wA = __expf(lA - mn);
      float wB = __expf(lB - mn);   // 0 when !two
      m = mn;
      s = s * sc + wA + wB;
      acc.x = acc.x * sc + wA * bf2f(vA.x) + wB * bf2f(vB.x);
      acc.y = acc.y * sc + wA * bf2f(vA.y) + wB * bf2f(vB.y);
      acc.z = acc.z * sc + wA * bf2f(vA.z) + wB * bf2f(vB.z);
      acc.w = acc.w * sc + wA * bf2f(vA.w) + wB * bf2f(vB.w);
    }
    float inv = 1.f / fmaxf(s, 1e-9f);
    acc.x *= inv; acc.y *= inv; acc.z *= inv; acc.w *= inv;
  }
  ushort4 o;
  o.x = f2bf(acc.x); o.y = f2bf(acc.y); o.z = f2bf(acc.z); o.w = f2bf(acc.w);
  *(ushort4*)(a.agg[r] + (size_t)node * 256 + lane * 4) = o;
}

// ---------------- msg transform on aggregates + relu + cross-etype mean -> t bf16 ------
struct MsgArgs {
  const unsigned short* aggA[3]; const unsigned short* aggB[3];
  const unsigned short* fA[3]; const unsigned short* fB[3];
  unsigned short* t[3];
  float scale[3];
  int N[3]; int bcum[4];
};
__global__ __launch_bounds__(256) void msg_transform_all(MsgArgs a) {
  int g = 0;
  while (g < 2 && (int)blockIdx.x >= a.bcum[g + 1]) g++;
  int local = blockIdx.x - a.bcum[g];
  const unsigned short* aggA = a.aggA[g];
  const unsigned short* aggB = a.aggB[g];
  const unsigned short* fA = a.fA[g];
  const unsigned short* fB = a.fB[g];
  unsigned short* t = a.t[g];
  float scale = a.scale[g];
  int N = a.N[g];
  int wave = threadIdx.x >> 6, lane = threadIdx.x & 63;
  int r0 = local * 64 + wave * 16;
  int arow = r0 + (lane & 15);
  bool valid = arow < N;
  int kofs = (lane >> 4) * 8;
  f32x4 z{};
#pragma unroll
  for (int h = 0; h < 8; h++) {
    bf16x8 aA{}, aB{};
    if (valid) {
      aA = *(const bf16x8*)(aggA + (size_t)arow * 256 + h * 32 + kofs);
      if (aggB) aB = *(const bf16x8*)(aggB + (size_t)arow * 256 + h * 32 + kofs);
    }
#pragma unroll
    for (int c = 0; c < 2; c++) {
      bf16x8 bA = *(const bf16x8*)(fA + ((h * 2 + c) * 64 + lane) * 8);
      f32x4 oA = __builtin_amdgcn_mfma_f32_16x16x32_bf16(aA, bA, z, 0, 0, 0);
      f32x4 oB = z;
      if (aggB) {
        bf16x8 bB = *(const bf16x8*)(fB + ((h * 2 + c) * 64 + lane) * 8);
        oB = __builtin_amdgcn_mfma_f32_16x16x32_bf16(aB, bB, z, 0, 0, 0);
      }
      int colc = h * 32 + c * 16 + (lane & 15);
#pragma unroll
      for (int rr = 0; rr < 4; rr++) {
        int row = r0 + (lane >> 4) * 4 + rr;
        if (row < N) {
          float v = fmaxf(oA[rr], 0.f) + fmaxf(oB[rr], 0.f);
          t[(size_t)row * 256 + colc] = f2bf(v * scale);
        }
      }
    }
  }
}

// ---------------- unified output GEMM + skip-blend + LayerNorm (1 dispatch) ------
struct OutAll {
  const unsigned short* tA[3]; const unsigned short* WT[3];
  const float* ba[3]; const float* feat[3];
  const float* gamma[3]; const float* beta[3];
  float* op[3];
  int M[3], bcum[4];
  const float* skipv;
};
__global__ __launch_bounds__(256) void out_all_ln(OutAll oa) {
  __shared__ unsigned short As[64 * 64];
  __shared__ unsigned short Bs[256 * 64];
  int g = 0;
  while (g < 2 && (int)blockIdx.x >= oa.bcum[g + 1]) g++;
  const int bm = (blockIdx.x - oa.bcum[g]) * 64;
  const unsigned short* tA = oa.tA[g];
  const unsigned short* WT = oa.WT[g];
  const int M = oa.M[g];
  const int tid = threadIdx.x, wave = tid >> 6, lane = tid & 63;
  f32x4 acc[16] = {};
  const int ar = wave * 16 + (lane & 15);
  const int swz = lane & 7;
  for (int k0 = 0; k0 < 256; k0 += 64) {
#pragma unroll
    for (int i = 0; i < 2; i++) {
      int c = tid + i * 256;
      int row = c >> 3, sl = c & 7;
      int srow = bm + row;
      bf16x8 av{};
      if (srow < M) av = *(const bf16x8*)(tA + (size_t)srow * 256 + k0 + sl * 8);
      *(bf16x8*)&As[row * 64 + (sl ^ (row & 7)) * 8] = av;
    }
#pragma unroll
    for (int i = 0; i < 8; i++) {
      int c = tid + i * 256;
      int row = c >> 3, sl = c & 7;
      bf16x8 bv = *(const bf16x8*)(WT + (size_t)row * 256 + k0 + sl * 8);
      *(bf16x8*)&Bs[row * 64 + (sl ^ (row & 7)) * 8] = bv;
    }
    __syncthreads();
#pragma unroll
    for (int kk = 0; kk < 2; kk++) {
      int slot = kk * 4 + (lane >> 4);
      bf16x8 a = *(const bf16x8*)&As[ar * 64 + ((slot ^ swz) * 8)];
#pragma unroll
      for (int nf = 0; nf < 16; nf++) {
        int br = nf * 16 + (lane & 15);
        bf16x8 b = *(const bf16x8*)&Bs[br * 64 + ((slot ^ swz) * 8)];
        acc[nf] = __builtin_amdgcn_mfma_f32_16x16x32_bf16(a, b, acc[nf], 0, 0, 0);
      }
    }
    __syncthreads();
  }
  const int c16 = lane & 15;
  float a_skip = 1.f / (1.f + __expf(-oa.skipv[g]));
  float one_m = 1.f - a_skip;
  const float* gamma = oa.gamma[g];
  const float* beta = oa.beta[g];
  const float* ba = oa.ba[g];
  const float* feat = oa.feat[g];
  float* outp = oa.op[g];
  float gg[16], bb[16], bia[16];
#pragma unroll
  for (int nf = 0; nf < 16; nf++) {
    gg[nf] = gamma[nf * 16 + c16];
    bb[nf] = beta[nf * 16 + c16];
    bia[nf] = ba[nf * 16 + c16];
  }
#pragma unroll
  for (int rr = 0; rr < 4; rr++) {
    int row = bm + wave * 16 + (lane >> 4) * 4 + rr;
    bool valid = row < M;
#pragma unroll
    for (int nf = 0; nf < 16; nf++) {
      float fv = valid ? feat[(size_t)row * 256 + nf * 16 + c16] : 0.f;
      acc[nf][rr] = (acc[nf][rr] + bia[nf]) * a_skip + fv * one_m;
    }
    float p = 0.f;
#pragma unroll
    for (int nf = 0; nf < 16; nf++) p += acc[nf][rr];
    p += __shfl_xor(p, 1, 16); p += __shfl_xor(p, 2, 16);
    p += __shfl_xor(p, 4, 16); p += __shfl_xor(p, 8, 16);
    float mu = p * (1.f / 256.f);
    float qv = 0.f;
#pragma unroll
    for (int nf = 0; nf < 16; nf++) { float dd = acc[nf][rr] - mu; qv += dd * dd; }
    qv += __shfl_xor(qv, 1, 16); qv += __shfl_xor(qv, 2, 16);
    qv += __shfl_xor(qv, 4, 16); qv += __shfl_xor(qv, 8, 16);
    float rstd = rsqrtf(qv * (1.f / 256.f) + 1e-5f);
    if (valid) {
#pragma unroll
      for (int nf = 0; nf < 16; nf++)
        outp[(size_t)row * 256 + nf * 16 + c16] = (acc[nf][rr] - mu) * rstd * gg[nf] + bb[nf];
    }
  }
}

extern "C" void kernel_launch(void* const* d_in, const int* in_sizes, int n_in,
                              void* d_out, int out_size, void* d_ws, size_t ws_size,
                              hipStream_t stream) {
  const float* feat_w = (const float*)d_in[0];
  const float* feat_t = (const float*)d_in[1];
  const float* feat_d = (const float*)d_in[2];
  const float* Wk = (const float*)d_in[3];
  const float* bk = (const float*)d_in[4];
  const float* Wq = (const float*)d_in[5];
  const float* bq = (const float*)d_in[6];
  const float* Wv = (const float*)d_in[7];
  const float* bv = (const float*)d_in[8];
  const float* Wa = (const float*)d_in[9];
  const float* ba = (const float*)d_in[10];
  const float* ln_scale = (const float*)d_in[11];
  const float* ln_bias = (const float*)d_in[12];
  const float* skip = (const float*)d_in[13];
  const float* rel_pri = (const float*)d_in[14];
  const float* rel_att = (const float*)d_in[15];
  const float* rel_msg = (const float*)d_in[16];
  const int* src_ww = (const int*)d_in[17];
  const int* dst_ww = (const int*)d_in[18];
  const int* src_wt = (const int*)d_in[19];
  const int* dst_wt = (const int*)d_in[20];
  const int* src_wd = (const int*)d_in[21];
  const int* dst_wd = (const int*)d_in[22];
  const int* src_tt = (const int*)d_in[23];
  const int* dst_tt = (const int*)d_in[24];
  const int* src_td = (const int*)d_in[25];
  const int* dst_td = (const int*)d_in[26];
  float* out = (float*)d_out;
  float* ws = (float*)d_ws;

  // ---- workspace (sizes in FLOAT units) ----
  size_t off = 0;
  auto allocF = [&](size_t nf) { float* p = ws + off; off += nf; return p; };
  unsigned short* kv_w = (unsigned short*)allocF(5120000);   // [20000][512] bf16 (k|v)
  unsigned short* kv_t = (unsigned short*)allocF(512000);    // [2000][512]
  unsigned short* qhat0 = (unsigned short*)allocF(2560000);
  unsigned short* qhat1 = (unsigned short*)allocF(256000);
  unsigned short* qhat2 = (unsigned short*)allocF(640000);
  unsigned short* qhat3 = (unsigned short*)allocF(256000);
  unsigned short* qhat4 = (unsigned short*)allocF(640000);
  unsigned short* aggr0 = (unsigned short*)allocF(2560000);
  unsigned short* aggr1 = (unsigned short*)allocF(256000);
  unsigned short* aggr2 = (unsigned short*)allocF(640000);
  unsigned short* aggr3 = (unsigned short*)allocF(256000);
  unsigned short* aggr4 = (unsigned short*)allocF(640000);
  unsigned short* t_word  = (unsigned short*)allocF(2560000);
  unsigned short* t_topic = (unsigned short*)allocF(256000);
  unsigned short* t_doc   = (unsigned short*)allocF(640000);
  unsigned short* WTw = (unsigned short*)allocF(98304);   // [768][256]:  qeff0 | k | v
  unsigned short* WTt = (unsigned short*)allocF(131072);  // [1024][256]: k | v | qeff1 | qeff3
  unsigned short* WTd = (unsigned short*)allocF(65536);   // [512][256]:  qeff2 | qeff4
  unsigned short* WTa = (unsigned short*)allocF(98304);   // 3 x 256x256
  unsigned short* wvp = (unsigned short*)allocF(20480);   // msg frag-packed
  float* bq_eff = allocF(1280);                           // 5 x 256 f32
  int* counts  = (int*)allocF(34000);
  int* cursor  = (int*)allocF(34000);
  int* offsets = (int*)allocF(34004);
  int* ssrc    = (int*)allocF(370000);

  dim3 b256(256);
  auto cdiv = [](int a, int b) { return (a + b - 1) / b; };

  // ---- weight packing ----
  Pack7 p7;
  p7.src[0] = Wk;           p7.dst[0] = WTw + 65536;    // word k
  p7.src[1] = Wv;           p7.dst[1] = WTw + 131072;   // word v
  p7.src[2] = Wk + 65536;   p7.dst[2] = WTt;            // topic k
  p7.src[3] = Wv + 65536;   p7.dst[3] = WTt + 65536;    // topic v
  p7.src[4] = Wa;           p7.dst[4] = WTa;
  p7.src[5] = Wa + 65536;   p7.dst[5] = WTa + 65536;
  p7.src[6] = Wa + 131072;  p7.dst[6] = WTa + 131072;
  pack_wt7<<<dim3(7, 8, 8), b256, 0, stream>>>(p7);
  {
    EffArgs ea;
    ea.wq[0] = Wq;           ea.bq[0] = bq;        ea.dst[0] = WTw;            // ww (word q)
    ea.wq[1] = Wq + 65536;   ea.bq[1] = bq + 256;  ea.dst[1] = WTt + 131072;   // wt (topic q)
    ea.wq[2] = Wq + 131072;  ea.bq[2] = bq + 512;  ea.dst[2] = WTd;            // wd (doc q)
    ea.wq[3] = Wq + 65536;   ea.bq[3] = bq + 256;  ea.dst[3] = WTt + 196608;   // tt (topic q)
    ea.wq[4] = Wq + 131072;  ea.bq[4] = bq + 512;  ea.dst[4] = WTd + 65536;    // td (doc q)
    ea.beff = bq_eff;
    ea.att = rel_att;
    wq_eff_kernel<<<cdiv(5 * 65536 + 1280, 256), b256, 0, stream>>>(ea);
  }
  pack_headw<<<160, b256, 0, stream>>>(rel_msg, wvp, 5);

  // ---- CSR build ----
  CsrDesc dsc;
  dsc.dst[0] = dst_ww; dsc.dst[1] = dst_wt; dsc.dst[2] = dst_wd; dsc.dst[3] = dst_tt; dsc.dst[4] = dst_td;
  dsc.src[0] = src_ww; dsc.src[1] = src_wt; dsc.src[2] = src_wd; dsc.src[3] = src_tt; dsc.src[4] = src_td;
  int Es[5] = {E_WW, E_WT, E_WD, E_TT, E_TD};
  int Ns[5] = {NW, NT, ND, NT, ND};
  int cb = 0;
  for (int r = 0; r < 5; r++) {
    dsc.E[r] = Es[r]; dsc.N[r] = Ns[r]; dsc.cbase[r] = cb;
    cb += Ns[r];
  }
  hipMemsetAsync(counts, 0, (size_t)68000 * sizeof(int), stream);
  hist5<<<cdiv(370000, 256), b256, 0, stream>>>(dsc, counts);
  scan_all<<<1, 1024, 0, stream>>>(counts, offsets, 34000);
  scatter5<<<cdiv(370000, 256), b256, 0, stream>>>(dsc, offsets, cursor, ssrc);

  // ---- unified projections (word: qhat0|k|v, topic: k|v|qhat1|qhat3, doc: qhat2|qhat4) ----
  {
    ProjAll pa;
    pa.A[0] = feat_w; pa.A[1] = feat_t; pa.A[2] = feat_d;
    pa.WT[0] = WTw;   pa.WT[1] = WTt;   pa.WT[2] = WTd;
    pa.M[0] = NW; pa.M[1] = NT; pa.M[2] = ND;
    // word segments
    pa.bias[0][0] = bq_eff;       pa.outp[0][0] = qhat0;      pa.ostride[0][0] = 256;
    pa.bias[0][1] = bk;           pa.outp[0][1] = kv_w;       pa.ostride[0][1] = 512;
    pa.bias[0][2] = bv;           pa.outp[0][2] = kv_w + 256; pa.ostride[0][2] = 512;
    pa.bias[0][3] = bq_eff;       pa.outp[0][3] = qhat0;      pa.ostride[0][3] = 256;  // unused
    // topic segments
    pa.bias[1][0] = bk + 256;     pa.outp[1][0] = kv_t;       pa.ostride[1][0] = 512;
    pa.bias[1][1] = bv + 256;     pa.outp[1][1] = kv_t + 256; pa.ostride[1][1] = 512;
    pa.bias[1][2] = bq_eff + 256; pa.outp[1][2] = qhat1;      pa.ostride[1][2] = 256;
    pa.bias[1][3] = bq_eff + 768; pa.outp[1][3] = qhat3;      pa.ostride[1][3] = 256;
    // doc segments
    pa.bias[2][0] = bq_eff + 512;  pa.outp[2][0] = qhat2;     pa.ostride[2][0] = 256;
    pa.bias[2][1] = bq_eff + 1024; pa.outp[2][1] = qhat4;     pa.ostride[2][1] = 256;
    pa.bias[2][2] = bq_eff;        pa.outp[2][2] = qhat2;     pa.ostride[2][2] = 256;  // unused
    pa.bias[2][3] = bq_eff;        pa.outp[2][3] = qhat2;     pa.ostride[2][3] = 256;  // unused
    pa.ncolb[0] = 12; pa.ncolb[1] = 16; pa.ncolb[2] = 8;
    int bc = 0;
    int nb0 = cdiv(NW, 64) * 12, nb1 = cdiv(NT, 64) * 16, nb2 = cdiv(ND, 64) * 8;
    pa.bcum[0] = 0; pa.bcum[1] = nb0; pa.bcum[2] = nb0 + nb1; pa.bcum[3] = nb0 + nb1 + nb2;
    bc = pa.bcum[3];
    proj_all<<<bc, b256, 0, stream>>>(pa);
  }

  int NdstA[5] = {NW, NT, ND, NT, ND};

  // ---- fused attention + softmax + raw-V aggregation ----
  {
    AttArgs aa;
    aa.qh[0] = qhat0; aa.qh[1] = qhat1; aa.qh[2] = qhat2; aa.qh[3] = qhat3; aa.qh[4] = qhat4;
    aa.kv[0] = aa.kv[1] = aa.kv[2] = kv_w; aa.kv[3] = aa.kv[4] = kv_t;
    unsigned short* aggs[5] = {aggr0, aggr1, aggr2, aggr3, aggr4};
    aa.ssrc = ssrc;
    int bc = 0;
    for (int r = 0; r < 5; r++) {
      aa.offs[r] = offsets + dsc.cbase[r];
      aa.agg[r] = aggs[r];
      aa.Ndst[r] = NdstA[r];
      aa.bcum[r] = bc; bc += cdiv(NdstA[r], 4);
    }
    aa.bcum[5] = bc;
    aa.pri = rel_pri;
    fused_att_agg<<<bc, b256, 0, stream>>>(aa);
  }

  // ---- msg transform + relu + cross-etype mean -> t (bf16) ----
  {
    MsgArgs ma;
    ma.aggA[0] = aggr0; ma.aggB[0] = nullptr;
    ma.fA[0] = wvp;             ma.fB[0] = wvp;
    ma.t[0] = t_word;  ma.scale[0] = 1.0f;  ma.N[0] = NW;
    ma.aggA[1] = aggr1; ma.aggB[1] = aggr3;
    ma.fA[1] = wvp + 8192;      ma.fB[1] = wvp + 3 * 8192;
    ma.t[1] = t_topic; ma.scale[1] = 0.5f;  ma.N[1] = NT;
    ma.aggA[2] = aggr2; ma.aggB[2] = aggr4;
    ma.fA[2] = wvp + 2 * 8192;  ma.fB[2] = wvp + 4 * 8192;
    ma.t[2] = t_doc;   ma.scale[2] = 0.5f;  ma.N[2] = ND;
    int bc = 0;
    for (int g = 0; g < 3; g++) { ma.bcum[g] = bc; bc += cdiv(ma.N[g], 64); }
    ma.bcum[3] = bc;
    msg_transform_all<<<bc, b256, 0, stream>>>(ma);
  }

  // ---- unified output GEMM + skip + LayerNorm ----
  {
    OutAll oa;
    oa.tA[0] = t_word;  oa.tA[1] = t_topic; oa.tA[2] = t_doc;
    oa.WT[0] = WTa; oa.WT[1] = WTa + 65536; oa.WT[2] = WTa + 131072;
    oa.ba[0] = ba; oa.ba[1] = ba + 256; oa.ba[2] = ba + 512;
    oa.feat[0] = feat_w; oa.feat[1] = feat_t; oa.feat[2] = feat_d;
    oa.gamma[0] = ln_scale; oa.gamma[1] = ln_scale + 256; oa.gamma[2] = ln_scale + 512;
    oa.beta[0] = ln_bias; oa.beta[1] = ln_bias + 256; oa.beta[2] = ln_bias + 512;
    oa.op[0] = out; oa.op[1] = out + (size_t)NW * 256; oa.op[2] = out + (size_t)(NW + NT) * 256;
    oa.M[0] = NW; oa.M[1] = NT; oa.M[2] = ND;
    int bc = 0;
    for (int g = 0; g < 3; g++) { oa.bcum[g] = bc; bc += cdiv(oa.M[g], 64); }
    oa.bcum[3] = bc;
    oa.skipv = skip;
    out_all_ln<<<bc, b256, 0, stream>>>(oa);
  }

  (void)in_sizes; (void)n_in; (void)out_size; (void)ws_size;
}

// Round 9
// 209.037 us; speedup vs baseline: 9.5185x; 1.0934x over previous
//
#include <hip/hip_runtime.h>

static constexpr int NW = 20000, NT = 2000, ND = 5000;
static constexpr int E_WW = 150000, E_WT = 80000, E_WD = 80000, E_TT = 20000, E_TD = 40000;

typedef short bf16x8 __attribute__((ext_vector_type(8)));
typedef float f32x4 __attribute__((ext_vector_type(4)));
typedef float f32x2 __attribute__((ext_vector_type(2)));

__device__ __forceinline__ unsigned short f2bf(float f) {
  union { float f; unsigned int u; } c; c.f = f;
  unsigned int u = c.u;
  u += 0x7fffu + ((u >> 16) & 1u);
  return (unsigned short)(u >> 16);
}
__device__ __forceinline__ float bf2f(unsigned short h) {
  union { unsigned int u; float f; } c; c.u = ((unsigned int)h) << 16; return c.f;
}
__device__ __forceinline__ bf16x8 pack8(float4 a, float4 b) {
  bf16x8 r;
  r[0] = (short)f2bf(a.x); r[1] = (short)f2bf(a.y); r[2] = (short)f2bf(a.z); r[3] = (short)f2bf(a.w);
  r[4] = (short)f2bf(b.x); r[5] = (short)f2bf(b.y); r[6] = (short)f2bf(b.z); r[7] = (short)f2bf(b.w);
  return r;
}
__device__ __forceinline__ unsigned char f2fp8(float x) {
  int p = __builtin_amdgcn_cvt_pk_fp8_f32(x, x, 0, false);
  return (unsigned char)(p & 0xff);
}

// ---------------- CSR descriptor ----------------
struct CsrDesc {
  const int* dst[5];
  const int* src[5];
  int E[5], N[5], cbase[5];
};

// ================= PREP mega-kernel: pack7 | wq_eff | pack_headw | hist =================
struct PrepArgs {
  // pack7: W[k][n] f32 -> WT[n][k] bf16
  const float* psrc[7]; unsigned short* pdst[7];
  // wq_eff
  const float* wq[5]; const float* bqp[5];
  unsigned short* qdst[5];
  float* beff;
  const float* att;
  // pack_headw (msg)
  const float* msg; unsigned short* wvp;
  // hist
  CsrDesc dsc;
  int* counts;
  int bEff, bHw, bHist, bTot;   // cumulative block starts
};
__global__ __launch_bounds__(256) void prep_kernel(PrepArgs a) {
  __shared__ float tile[32][33];
  int b = blockIdx.x;
  int tid = threadIdx.x;
  if (b < a.bEff) {
    // ---- pack7: b -> (m, bk, bn) ----
    int m = b >> 6, bk = ((b >> 3) & 7) * 32, bn = (b & 7) * 32;
    const float* W = a.psrc[m];
    unsigned short* WT = a.pdst[m];
    int tx = tid & 31, ty = tid >> 5;
#pragma unroll
    for (int i = 0; i < 32; i += 8)
      tile[ty + i][tx] = W[(size_t)(bk + ty + i) * 256 + bn + tx];
    __syncthreads();
#pragma unroll
    for (int i = 0; i < 32; i += 8)
      WT[(size_t)(bn + ty + i) * 256 + bk + tx] = f2bf(tile[tx][ty + i]);
  } else if (b < a.bHw) {
    // ---- wq_eff: WTe[r][n][kk] = sum_d Wq[kk][h*32+d]*att[r][h][j][d] ----
    int t = (b - a.bEff) * 256 + tid;
    if (t < 5 * 65536) {
      int r = t >> 16, rem = t & 65535;
      int n = rem >> 8, kk = rem & 255;
      int h = n >> 5, j = n & 31;
      const float* wrow = a.wq[r] + kk * 256 + h * 32;
      const float* arow = a.att + r * 8192 + h * 1024 + j * 32;
      float s = 0.f;
#pragma unroll
      for (int d = 0; d < 32; d += 4) {
        float4 wv = *(const float4*)(wrow + d);
        float4 av = *(const float4*)(arow + d);
        s += wv.x * av.x + wv.y * av.y + wv.z * av.z + wv.w * av.w;
      }
      a.qdst[r][n * 256 + kk] = f2bf(s);
    } else {
      int idx = t - 5 * 65536;
      if (idx < 1280) {
        int r = idx >> 8, n = idx & 255;
        int h = n >> 5, j = n & 31;
        const float* brow = a.bqp[r] + h * 32;
        const float* arow = a.att + r * 8192 + h * 1024 + j * 32;
        float s = 0.f;
#pragma unroll
        for (int d = 0; d < 32; d += 4) {
          float4 bv = *(const float4*)(brow + d);
          float4 av = *(const float4*)(arow + d);
          s += bv.x * av.x + bv.y * av.y + bv.z * av.z + bv.w * av.w;
        }
        a.beff[r * 256 + n] = s;
      }
    }
  } else if (b < a.bHist) {
    // ---- pack_headw: msg weights -> MFMA B-frag order ----
    int t = (b - a.bHw) * 256 + tid;
    if (t < 5 * 8192) {
      int m = t >> 13, rem = t & 8191;
      int hc = rem >> 9, idx = rem & 511;
      int lane = idx >> 3, j = idx & 7;
      int h = hc >> 1, c = hc & 1;
      int k = (lane >> 4) * 8 + j, n = c * 16 + (lane & 15);
      a.wvp[t] = f2bf(a.msg[(size_t)m * 8192 + h * 1024 + k * 32 + n]);
    }
  } else {
    // ---- hist ----
    int t = (b - a.bHist) * 256 + tid;
    int r = 0, base = 0;
    while (r < 5 && t >= base + a.dsc.E[r]) { base += a.dsc.E[r]; r++; }
    if (r >= 5) return;
    int e = t - base;
    atomicAdd(a.counts + a.dsc.cbase[r] + a.dsc.dst[r][e], 1);
  }
}

// ================= unified projection GEMM (+ embedded scan block) =================
// All output rows are 512 BYTES. esz per segment: 2 = bf16, 1 = fp8(e4m3).
struct ProjAll {
  const float* A[3];
  const unsigned short* WT[3];
  const float* bias[3][4];
  unsigned char* outB[3][4];
  int esz[3][4];
  int M[3], ncolb[3], bcum[4];
  // scan (extra block)
  const int* counts; int* offsets; int scanN;
};
__global__ __launch_bounds__(256) void proj_all(ProjAll pa) {
  __shared__ unsigned short As[64 * 64];
  __shared__ unsigned short Bs[64 * 64];
  __shared__ int wpart2[4];
  __shared__ int carry2;
  const int tid = threadIdx.x;
  if ((int)blockIdx.x >= pa.bcum[3]) {
    // ---- embedded serial scan over concatenated counts ----
    int lane = tid & 63, w = tid >> 6;
    if (tid == 0) carry2 = 0;
    __syncthreads();
    const int N = pa.scanN;
    for (int base = 0; base < N; base += 1024) {
      int idx = base + tid * 4;
      int v0 = 0, v1 = 0, v2 = 0, v3 = 0;
      if (idx + 3 < N) {
        int4 t4 = *(const int4*)(pa.counts + idx);
        v0 = t4.x; v1 = t4.y; v2 = t4.z; v3 = t4.w;
      } else if (idx < N) {
        v0 = pa.counts[idx];
        if (idx + 1 < N) v1 = pa.counts[idx + 1];
        if (idx + 2 < N) v2 = pa.counts[idx + 2];
      }
      int ts = v0 + v1 + v2 + v3;
      int x = ts;
#pragma unroll
      for (int d = 1; d < 64; d <<= 1) {
        int t = __shfl_up(x, d, 64);
        if (lane >= d) x += t;
      }
      if (lane == 63) wpart2[w] = x;
      __syncthreads();
      if (tid == 0) {
        int s = 0;
#pragma unroll
        for (int j = 0; j < 4; j++) { int t = wpart2[j]; wpart2[j] = s; s += t; }
      }
      __syncthreads();
      int excl = carry2 + wpart2[w] + (x - ts);
      if (idx < N)     pa.offsets[idx]     = excl;
      if (idx + 1 < N) pa.offsets[idx + 1] = excl + v0;
      if (idx + 2 < N) pa.offsets[idx + 2] = excl + v0 + v1;
      if (idx + 3 < N) pa.offsets[idx + 3] = excl + v0 + v1 + v2;
      __syncthreads();
      if (tid == 255) carry2 = excl + ts;
      __syncthreads();
    }
    if (tid == 0) pa.offsets[N] = carry2;
    return;
  }
  int nt = 0;
  while (nt < 2 && (int)blockIdx.x >= pa.bcum[nt + 1]) nt++;
  int local = blockIdx.x - pa.bcum[nt];
  int ncolb = pa.ncolb[nt];
  int bmi = local / ncolb, bnb = local % ncolb;
  const int bm = bmi * 64, bn = bnb * 64;
  const float* A = pa.A[nt];
  const unsigned short* WT = pa.WT[nt];
  const int M = pa.M[nt];
  const int wave = tid >> 6, lane = tid & 63;
  f32x4 acc[4] = {};
  const int ar = wave * 16 + (lane & 15);
  const int swz = lane & 7;
  for (int k0 = 0; k0 < 256; k0 += 64) {
#pragma unroll
    for (int i = 0; i < 2; i++) {
      int c = tid + i * 256;
      int row = c >> 3, sl = c & 7;
      int srow = bm + row;
      float4 a0 = make_float4(0.f, 0.f, 0.f, 0.f), a1 = a0;
      if (srow < M) {
        a0 = *(const float4*)(A + (size_t)srow * 256 + k0 + sl * 8);
        a1 = *(const float4*)(A + (size_t)srow * 256 + k0 + sl * 8 + 4);
      }
      *(bf16x8*)&As[row * 64 + (sl ^ (row & 7)) * 8] = pack8(a0, a1);
      bf16x8 bv = *(const bf16x8*)(WT + (size_t)(bn + row) * 256 + k0 + sl * 8);
      *(bf16x8*)&Bs[row * 64 + (sl ^ (row & 7)) * 8] = bv;
    }
    __syncthreads();
#pragma unroll
    for (int kk = 0; kk < 2; kk++) {
      int slot = kk * 4 + (lane >> 4);
      bf16x8 av = *(const bf16x8*)&As[ar * 64 + ((slot ^ swz) * 8)];
#pragma unroll
      for (int nf = 0; nf < 4; nf++) {
        int br = nf * 16 + (lane & 15);
        bf16x8 bv = *(const bf16x8*)&Bs[br * 64 + ((slot ^ swz) * 8)];
        acc[nf] = __builtin_amdgcn_mfma_f32_16x16x32_bf16(av, bv, acc[nf], 0, 0, 0);
      }
    }
    __syncthreads();
  }
  const int col = lane & 15;
  const int seg = bnb >> 2;
  const float* bias = pa.bias[nt][seg];
  unsigned char* outB = pa.outB[nt][seg];
  const int esz = pa.esz[nt][seg];
  const int cbase = (bnb & 3) * 64;
#pragma unroll
  for (int nf = 0; nf < 4; nf++) {
    float bsv = bias[cbase + nf * 16 + col];
    int idx = cbase + nf * 16 + col;
#pragma unroll
    for (int rr = 0; rr < 4; rr++) {
      int row = bm + wave * 16 + (lane >> 4) * 4 + rr;
      if (row < M) {
        float v = acc[nf][rr] + bsv;
        if (esz == 2) *(unsigned short*)(outB + (size_t)row * 512 + idx * 2) = f2bf(v);
        else          outB[(size_t)row * 512 + idx] = f2fp8(v);
      }
    }
  }
}

// ================= scatter =================
__global__ void scatter5(CsrDesc d, const int* __restrict__ offsets, int* __restrict__ cursor,
                         int* __restrict__ ssrc) {
  int t = blockIdx.x * blockDim.x + threadIdx.x;
  int r = 0, base = 0;
  while (r < 5 && t >= base + d.E[r]) { base += d.E[r]; r++; }
  if (r >= 5) return;
  int e = t - base;
  int dn = d.dst[r][e];
  int pos = offsets[d.cbase[r] + dn] + atomicAdd(cursor + d.cbase[r] + dn, 1);
  ssrc[pos] = d.src[r][e];
}

// ================= fused attention + online softmax + fp8 k/v aggregation =================
// kv8: [node][512B] = 256B fp8 k | 256B fp8 v.
struct AttArgs {
  const unsigned short* qh[5]; const unsigned char* kv8[5];
  const int* offs[5]; unsigned short* agg[5];
  const int* ssrc;
  const float* pri;
  int bcum[6]; int Ndst[5];
};
__global__ __launch_bounds__(256) void fused_att_agg(AttArgs a) {
  int r = 0;
  while (r < 4 && (int)blockIdx.x >= a.bcum[r + 1]) r++;
  int wave = threadIdx.x >> 6, lane = threadIdx.x & 63;
  int node = (blockIdx.x - a.bcum[r]) * 4 + wave;
  if (node >= a.Ndst[r]) return;
  const unsigned short* qh = a.qh[r];
  const unsigned char* kvb = a.kv8[r];
  const int* ssrc = a.ssrc;
  const int* offs = a.offs[r];
  int h = lane >> 3;
  float prih = a.pri[r * 8 + h] * 0.17677669529663687f;  // pri/sqrt(32)
  int r0 = offs[node], r1 = offs[node + 1];
  float4 acc = make_float4(0.f, 0.f, 0.f, 0.f);
  if (r0 < r1) {
    ushort4 qv = *(const ushort4*)(qh + (size_t)node * 256 + lane * 4);
    float q0 = bf2f(qv.x), q1 = bf2f(qv.y), q2 = bf2f(qv.z), q3 = bf2f(qv.w);
    float m = -1e30f, s = 0.f;
    for (int i = r0; i < r1; i += 2) {
      int sA = ssrc[i];
      bool two = (i + 1 < r1);
      int sB = two ? ssrc[i + 1] : sA;
      const unsigned char* pA = kvb + (size_t)sA * 512 + lane * 4;
      const unsigned char* pB = kvb + (size_t)sB * 512 + lane * 4;
      unsigned int kuA = *(const unsigned int*)pA;
      unsigned int kuB = *(const unsigned int*)pB;
      unsigned int vuA = *(const unsigned int*)(pA + 256);
      unsigned int vuB = *(const unsigned int*)(pB + 256);
      f32x2 ka01 = __builtin_amdgcn_cvt_pk_f32_fp8((int)kuA, false);
      f32x2 ka23 = __builtin_amdgcn_cvt_pk_f32_fp8((int)kuA, true);
      f32x2 kb01 = __builtin_amdgcn_cvt_pk_f32_fp8((int)kuB, false);
      f32x2 kb23 = __builtin_amdgcn_cvt_pk_f32_fp8((int)kuB, true);
      float dA = q0 * ka01[0] + q1 * ka01[1] + q2 * ka23[0] + q3 * ka23[1];
      float dB = q0 * kb01[0] + q1 * kb01[1] + q2 * kb23[0] + q3 * kb23[1];
      dA += __shfl_xor(dA, 1, 64); dB += __shfl_xor(dB, 1, 64);
      dA += __shfl_xor(dA, 2, 64); dB += __shfl_xor(dB, 2, 64);
      dA += __shfl_xor(dA, 4, 64); dB += __shfl_xor(dB, 4, 64);
      float lA = dA * prih;
      float lB = two ? dB * prih : -1e30f;
      float mn = fmaxf(m, fmaxf(lA, lB));
      float sc = __expf(m - mn);
      float wA = __expf(lA - mn);
      float wB = __expf(lB - mn);
      m = mn;
      s = s * sc + wA + wB;
      f32x2 va01 = __builtin_amdgcn_cvt_pk_f32_fp8((int)vuA, false);
      f32x2 va23 = __builtin_amdgcn_cvt_pk_f32_fp8((int)vuA, true);
      f32x2 vb01 = __builtin_amdgcn_cvt_pk_f32_fp8((int)vuB, false);
      f32x2 vb23 = __builtin_amdgcn_cvt_pk_f32_fp8((int)vuB, true);
      acc.x = acc.x * sc + wA * va01[0] + wB * vb01[0];
      acc.y = acc.y * sc + wA * va01[1] + wB * vb01[1];
      acc.z = acc.z * sc + wA * va23[0] + wB * vb23[0];
      acc.w = acc.w * sc + wA * va23[1] + wB * vb23[1];
    }
    float inv = 1.f / fmaxf(s, 1e-9f);
    acc.x *= inv; acc.y *= inv; acc.z *= inv; acc.w *= inv;
  }
  ushort4 o;
  o.x = f2bf(acc.x); o.y = f2bf(acc.y); o.z = f2bf(acc.z); o.w = f2bf(acc.w);
  *(ushort4*)(a.agg[r] + (size_t)node * 256 + lane * 4) = o;
}

// ================= msg transform + relu + cross-etype mean -> t bf16 =================
struct MsgArgs {
  const unsigned short* aggA[3]; const unsigned short* aggB[3];
  const unsigned short* fA[3]; const unsigned short* fB[3];
  unsigned short* t[3];
  float scale[3];
  int N[3]; int bcum[4];
};
__global__ __launch_bounds__(256) void msg_transform_all(MsgArgs a) {
  int g = 0;
  while (g < 2 && (int)blockIdx.x >= a.bcum[g + 1]) g++;
  int local = blockIdx.x - a.bcum[g];
  const unsigned short* aggA = a.aggA[g];
  const unsigned short* aggB = a.aggB[g];
  const unsigned short* fA = a.fA[g];
  const unsigned short* fB = a.fB[g];
  unsigned short* t = a.t[g];
  float scale = a.scale[g];
  int N = a.N[g];
  int wave = threadIdx.x >> 6, lane = threadIdx.x & 63;
  int r0 = local * 64 + wave * 16;
  int arow = r0 + (lane & 15);
  bool valid = arow < N;
  int kofs = (lane >> 4) * 8;
  f32x4 z{};
#pragma unroll
  for (int h = 0; h < 8; h++) {
    bf16x8 aA{}, aB{};
    if (valid) {
      aA = *(const bf16x8*)(aggA + (size_t)arow * 256 + h * 32 + kofs);
      if (aggB) aB = *(const bf16x8*)(aggB + (size_t)arow * 256 + h * 32 + kofs);
    }
#pragma unroll
    for (int c = 0; c < 2; c++) {
      bf16x8 bA = *(const bf16x8*)(fA + ((h * 2 + c) * 64 + lane) * 8);
      f32x4 oA = __builtin_amdgcn_mfma_f32_16x16x32_bf16(aA, bA, z, 0, 0, 0);
      f32x4 oB = z;
      if (aggB) {
        bf16x8 bB = *(const bf16x8*)(fB + ((h * 2 + c) * 64 + lane) * 8);
        oB = __builtin_amdgcn_mfma_f32_16x16x32_bf16(aB, bB, z, 0, 0, 0);
      }
      int colc = h * 32 + c * 16 + (lane & 15);
#pragma unroll
      for (int rr = 0; rr < 4; rr++) {
        int row = r0 + (lane >> 4) * 4 + rr;
        if (row < N) {
          float v = fmaxf(oA[rr], 0.f) + fmaxf(oB[rr], 0.f);
          t[(size_t)row * 256 + colc] = f2bf(v * scale);
        }
      }
    }
  }
}

// ================= unified output GEMM + skip-blend + LayerNorm =================
struct OutAll {
  const unsigned short* tA[3]; const unsigned short* WT[3];
  const float* ba[3]; const float* feat[3];
  const float* gamma[3]; const float* beta[3];
  float* op[3];
  int M[3], bcum[4];
  const float* skipv;
};
__global__ __launch_bounds__(256) void out_all_ln(OutAll oa) {
  __shared__ unsigned short As[64 * 64];
  __shared__ unsigned short Bs[256 * 64];
  int g = 0;
  while (g < 2 && (int)blockIdx.x >= oa.bcum[g + 1]) g++;
  const int bm = (blockIdx.x - oa.bcum[g]) * 64;
  const unsigned short* tA = oa.tA[g];
  const unsigned short* WT = oa.WT[g];
  const int M = oa.M[g];
  const int tid = threadIdx.x, wave = tid >> 6, lane = tid & 63;
  f32x4 acc[16] = {};
  const int ar = wave * 16 + (lane & 15);
  const int swz = lane & 7;
  for (int k0 = 0; k0 < 256; k0 += 64) {
#pragma unroll
    for (int i = 0; i < 2; i++) {
      int c = tid + i * 256;
      int row = c >> 3, sl = c & 7;
      int srow = bm + row;
      bf16x8 av{};
      if (srow < M) av = *(const bf16x8*)(tA + (size_t)srow * 256 + k0 + sl * 8);
      *(bf16x8*)&As[row * 64 + (sl ^ (row & 7)) * 8] = av;
    }
#pragma unroll
    for (int i = 0; i < 8; i++) {
      int c = tid + i * 256;
      int row = c >> 3, sl = c & 7;
      bf16x8 bv = *(const bf16x8*)(WT + (size_t)row * 256 + k0 + sl * 8);
      *(bf16x8*)&Bs[row * 64 + (sl ^ (row & 7)) * 8] = bv;
    }
    __syncthreads();
#pragma unroll
    for (int kk = 0; kk < 2; kk++) {
      int slot = kk * 4 + (lane >> 4);
      bf16x8 av = *(const bf16x8*)&As[ar * 64 + ((slot ^ swz) * 8)];
#pragma unroll
      for (int nf = 0; nf < 16; nf++) {
        int br = nf * 16 + (lane & 15);
        bf16x8 bv = *(const bf16x8*)&Bs[br * 64 + ((slot ^ swz) * 8)];
        acc[nf] = __builtin_amdgcn_mfma_f32_16x16x32_bf16(av, bv, acc[nf], 0, 0, 0);
      }
    }
    __syncthreads();
  }
  const int c16 = lane & 15;
  float a_skip = 1.f / (1.f + __expf(-oa.skipv[g]));
  float one_m = 1.f - a_skip;
  const float* gamma = oa.gamma[g];
  const float* beta = oa.beta[g];
  const float* ba = oa.ba[g];
  const float* feat = oa.feat[g];
  float* outp = oa.op[g];
  float gg[16], bb[16], bia[16];
#pragma unroll
  for (int nf = 0; nf < 16; nf++) {
    gg[nf] = gamma[nf * 16 + c16];
    bb[nf] = beta[nf * 16 + c16];
    bia[nf] = ba[nf * 16 + c16];
  }
#pragma unroll
  for (int rr = 0; rr < 4; rr++) {
    int row = bm + wave * 16 + (lane >> 4) * 4 + rr;
    bool valid = row < M;
#pragma unroll
    for (int nf = 0; nf < 16; nf++) {
      float fv = valid ? feat[(size_t)row * 256 + nf * 16 + c16] : 0.f;
      acc[nf][rr] = (acc[nf][rr] + bia[nf]) * a_skip + fv * one_m;
    }
    float p = 0.f;
#pragma unroll
    for (int nf = 0; nf < 16; nf++) p += acc[nf][rr];
    p += __shfl_xor(p, 1, 16); p += __shfl_xor(p, 2, 16);
    p += __shfl_xor(p, 4, 16); p += __shfl_xor(p, 8, 16);
    float mu = p * (1.f / 256.f);
    float qv = 0.f;
#pragma unroll
    for (int nf = 0; nf < 16; nf++) { float dd = acc[nf][rr] - mu; qv += dd * dd; }
    qv += __shfl_xor(qv, 1, 16); qv += __shfl_xor(qv, 2, 16);
    qv += __shfl_xor(qv, 4, 16); qv += __shfl_xor(qv, 8, 16);
    float rstd = rsqrtf(qv * (1.f / 256.f) + 1e-5f);
    if (valid) {
#pragma unroll
      for (int nf = 0; nf < 16; nf++)
        outp[(size_t)row * 256 + nf * 16 + c16] = (acc[nf][rr] - mu) * rstd * gg[nf] + bb[nf];
    }
  }
}

extern "C" void kernel_launch(void* const* d_in, const int* in_sizes, int n_in,
                              void* d_out, int out_size, void* d_ws, size_t ws_size,
                              hipStream_t stream) {
  const float* feat_w = (const float*)d_in[0];
  const float* feat_t = (const float*)d_in[1];
  const float* feat_d = (const float*)d_in[2];
  const float* Wk = (const float*)d_in[3];
  const float* bk = (const float*)d_in[4];
  const float* Wq = (const float*)d_in[5];
  const float* bq = (const float*)d_in[6];
  const float* Wv = (const float*)d_in[7];
  const float* bv = (const float*)d_in[8];
  const float* Wa = (const float*)d_in[9];
  const float* ba = (const float*)d_in[10];
  const float* ln_scale = (const float*)d_in[11];
  const float* ln_bias = (const float*)d_in[12];
  const float* skip = (const float*)d_in[13];
  const float* rel_pri = (const float*)d_in[14];
  const float* rel_att = (const float*)d_in[15];
  const float* rel_msg = (const float*)d_in[16];
  const int* src_ww = (const int*)d_in[17];
  const int* dst_ww = (const int*)d_in[18];
  const int* src_wt = (const int*)d_in[19];
  const int* dst_wt = (const int*)d_in[20];
  const int* src_wd = (const int*)d_in[21];
  const int* dst_wd = (const int*)d_in[22];
  const int* src_tt = (const int*)d_in[23];
  const int* dst_tt = (const int*)d_in[24];
  const int* src_td = (const int*)d_in[25];
  const int* dst_td = (const int*)d_in[26];
  float* out = (float*)d_out;
  float* ws = (float*)d_ws;

  // ---- workspace (sizes in FLOAT units) ----
  size_t off = 0;
  auto allocF = [&](size_t nf) { float* p = ws + off; off += nf; return p; };
  unsigned char* kv_w = (unsigned char*)allocF(2560000);   // [20000][512B] fp8 k|v
  unsigned char* kv_t = (unsigned char*)allocF(256000);    // [2000][512B]
  unsigned short* qhat0 = (unsigned short*)allocF(2560000);
  unsigned short* qhat1 = (unsigned short*)allocF(256000);
  unsigned short* qhat2 = (unsigned short*)allocF(640000);
  unsigned short* qhat3 = (unsigned short*)allocF(256000);
  unsigned short* qhat4 = (unsigned short*)allocF(640000);
  unsigned short* aggr0 = (unsigned short*)allocF(2560000);
  unsigned short* aggr1 = (unsigned short*)allocF(256000);
  unsigned short* aggr2 = (unsigned short*)allocF(640000);
  unsigned short* aggr3 = (unsigned short*)allocF(256000);
  unsigned short* aggr4 = (unsigned short*)allocF(640000);
  unsigned short* t_word  = (unsigned short*)allocF(2560000);
  unsigned short* t_topic = (unsigned short*)allocF(256000);
  unsigned short* t_doc   = (unsigned short*)allocF(640000);
  unsigned short* WTw = (unsigned short*)allocF(98304);   // [768][256]:  qeff0 | k | v
  unsigned short* WTt = (unsigned short*)allocF(131072);  // [1024][256]: k | v | qeff1 | qeff3
  unsigned short* WTd = (unsigned short*)allocF(65536);   // [512][256]:  qeff2 | qeff4
  unsigned short* WTa = (unsigned short*)allocF(98304);   // 3 x 256x256
  unsigned short* wvp = (unsigned short*)allocF(20480);   // msg frag-packed
  float* bq_eff = allocF(1280);                           // 5 x 256 f32
  int* counts  = (int*)allocF(34000);
  int* cursor  = (int*)allocF(34000);
  int* offsets = (int*)allocF(34004);
  int* ssrc    = (int*)allocF(370000);

  dim3 b256(256);
  auto cdiv = [](int a, int b) { return (a + b - 1) / b; };

  // ---- CSR descriptor ----
  CsrDesc dsc;
  dsc.dst[0] = dst_ww; dsc.dst[1] = dst_wt; dsc.dst[2] = dst_wd; dsc.dst[3] = dst_tt; dsc.dst[4] = dst_td;
  dsc.src[0] = src_ww; dsc.src[1] = src_wt; dsc.src[2] = src_wd; dsc.src[3] = src_tt; dsc.src[4] = src_td;
  int Es[5] = {E_WW, E_WT, E_WD, E_TT, E_TD};
  int Ns[5] = {NW, NT, ND, NT, ND};
  int cb = 0;
  for (int r = 0; r < 5; r++) {
    dsc.E[r] = Es[r]; dsc.N[r] = Ns[r]; dsc.cbase[r] = cb;
    cb += Ns[r];
  }

  hipMemsetAsync(counts, 0, (size_t)68000 * sizeof(int), stream);  // counts + cursor

  // ---- prep mega-kernel ----
  {
    PrepArgs pr;
    pr.psrc[0] = Wk;           pr.pdst[0] = WTw + 65536;    // word k
    pr.psrc[1] = Wv;           pr.pdst[1] = WTw + 131072;   // word v
    pr.psrc[2] = Wk + 65536;   pr.pdst[2] = WTt;            // topic k
    pr.psrc[3] = Wv + 65536;   pr.pdst[3] = WTt + 65536;    // topic v
    pr.psrc[4] = Wa;           pr.pdst[4] = WTa;
    pr.psrc[5] = Wa + 65536;   pr.pdst[5] = WTa + 65536;
    pr.psrc[6] = Wa + 131072;  pr.pdst[6] = WTa + 131072;
    pr.wq[0] = Wq;           pr.bqp[0] = bq;        pr.qdst[0] = WTw;            // ww
    pr.wq[1] = Wq + 65536;   pr.bqp[1] = bq + 256;  pr.qdst[1] = WTt + 131072;   // wt
    pr.wq[2] = Wq + 131072;  pr.bqp[2] = bq + 512;  pr.qdst[2] = WTd;            // wd
    pr.wq[3] = Wq + 65536;   pr.bqp[3] = bq + 256;  pr.qdst[3] = WTt + 196608;   // tt
    pr.wq[4] = Wq + 131072;  pr.bqp[4] = bq + 512;  pr.qdst[4] = WTd + 65536;    // td
    pr.beff = bq_eff;
    pr.att = rel_att;
    pr.msg = rel_msg; pr.wvp = wvp;
    pr.dsc = dsc; pr.counts = counts;
    int nPack = 7 * 64;                         // 448
    int nEff  = cdiv(5 * 65536 + 1280, 256);    // 1285
    int nHw   = cdiv(5 * 8192, 256);            // 160
    int nHist = cdiv(370000, 256);              // 1446
    pr.bEff  = nPack;
    pr.bHw   = nPack + nEff;
    pr.bHist = nPack + nEff + nHw;
    pr.bTot  = nPack + nEff + nHw + nHist;
    prep_kernel<<<pr.bTot, b256, 0, stream>>>(pr);
  }

  // ---- unified projections (+ scan block) ----
  {
    ProjAll pa;
    pa.A[0] = feat_w; pa.A[1] = feat_t; pa.A[2] = feat_d;
    pa.WT[0] = WTw;   pa.WT[1] = WTt;   pa.WT[2] = WTd;
    pa.M[0] = NW; pa.M[1] = NT; pa.M[2] = ND;
    // word segments: qeff0 (bf16) | k (fp8) | v (fp8)
    pa.bias[0][0] = bq_eff;       pa.outB[0][0] = (unsigned char*)qhat0; pa.esz[0][0] = 2;
    pa.bias[0][1] = bk;           pa.outB[0][1] = kv_w;                  pa.esz[0][1] = 1;
    pa.bias[0][2] = bv;           pa.outB[0][2] = kv_w + 256;            pa.esz[0][2] = 1;
    pa.bias[0][3] = bq_eff;       pa.outB[0][3] = (unsigned char*)qhat0; pa.esz[0][3] = 2; // unused
    // topic segments: k | v | qeff1 | qeff3
    pa.bias[1][0] = bk + 256;     pa.outB[1][0] = kv_t;                  pa.esz[1][0] = 1;
    pa.bias[1][1] = bv + 256;     pa.outB[1][1] = kv_t + 256;            pa.esz[1][1] = 1;
    pa.bias[1][2] = bq_eff + 256; pa.outB[1][2] = (unsigned char*)qhat1; pa.esz[1][2] = 2;
    pa.bias[1][3] = bq_eff + 768; pa.outB[1][3] = (unsigned char*)qhat3; pa.esz[1][3] = 2;
    // doc segments: qeff2 | qeff4
    pa.bias[2][0] = bq_eff + 512;  pa.outB[2][0] = (unsigned char*)qhat2; pa.esz[2][0] = 2;
    pa.bias[2][1] = bq_eff + 1024; pa.outB[2][1] = (unsigned char*)qhat4; pa.esz[2][1] = 2;
    pa.bias[2][2] = bq_eff;        pa.outB[2][2] = (unsigned char*)qhat2; pa.esz[2][2] = 2; // unused
    pa.bias[2][3] = bq_eff;        pa.outB[2][3] = (unsigned char*)qhat2; pa.esz[2][3] = 2; // unused
    pa.ncolb[0] = 12; pa.ncolb[1] = 16; pa.ncolb[2] = 8;
    int nb0 = cdiv(NW, 64) * 12, nb1 = cdiv(NT, 64) * 16, nb2 = cdiv(ND, 64) * 8;
    pa.bcum[0] = 0; pa.bcum[1] = nb0; pa.bcum[2] = nb0 + nb1; pa.bcum[3] = nb0 + nb1 + nb2;
    pa.counts = counts; pa.offsets = offsets; pa.scanN = 34000;
    proj_all<<<pa.bcum[3] + 1, b256, 0, stream>>>(pa);
  }

  // ---- scatter ----
  scatter5<<<cdiv(370000, 256), b256, 0, stream>>>(dsc, offsets, cursor, ssrc);

  int NdstA[5] = {NW, NT, ND, NT, ND};

  // ---- fused attention + softmax + fp8 aggregation ----
  {
    AttArgs aa;
    aa.qh[0] = qhat0; aa.qh[1] = qhat1; aa.qh[2] = qhat2; aa.qh[3] = qhat3; aa.qh[4] = qhat4;
    aa.kv8[0] = aa.kv8[1] = aa.kv8[2] = kv_w; aa.kv8[3] = aa.kv8[4] = kv_t;
    unsigned short* aggs[5] = {aggr0, aggr1, aggr2, aggr3, aggr4};
    aa.ssrc = ssrc;
    int bc = 0;
    for (int r = 0; r < 5; r++) {
      aa.offs[r] = offsets + dsc.cbase[r];
      aa.agg[r] = aggs[r];
      aa.Ndst[r] = NdstA[r];
      aa.bcum[r] = bc; bc += cdiv(NdstA[r], 4);
    }
    aa.bcum[5] = bc;
    aa.pri = rel_pri;
    fused_att_agg<<<bc, b256, 0, stream>>>(aa);
  }

  // ---- msg transform + relu + cross-etype mean ----
  {
    MsgArgs ma;
    ma.aggA[0] = aggr0; ma.aggB[0] = nullptr;
    ma.fA[0] = wvp;             ma.fB[0] = wvp;
    ma.t[0] = t_word;  ma.scale[0] = 1.0f;  ma.N[0] = NW;
    ma.aggA[1] = aggr1; ma.aggB[1] = aggr3;
    ma.fA[1] = wvp + 8192;      ma.fB[1] = wvp + 3 * 8192;
    ma.t[1] = t_topic; ma.scale[1] = 0.5f;  ma.N[1] = NT;
    ma.aggA[2] = aggr2; ma.aggB[2] = aggr4;
    ma.fA[2] = wvp + 2 * 8192;  ma.fB[2] = wvp + 4 * 8192;
    ma.t[2] = t_doc;   ma.scale[2] = 0.5f;  ma.N[2] = ND;
    int bc = 0;
    for (int g = 0; g < 3; g++) { ma.bcum[g] = bc; bc += cdiv(ma.N[g], 64); }
    ma.bcum[3] = bc;
    msg_transform_all<<<bc, b256, 0, stream>>>(ma);
  }

  // ---- unified output GEMM + skip + LayerNorm ----
  {
    OutAll oa;
    oa.tA[0] = t_word;  oa.tA[1] = t_topic; oa.tA[2] = t_doc;
    oa.WT[0] = WTa; oa.WT[1] = WTa + 65536; oa.WT[2] = WTa + 131072;
    oa.ba[0] = ba; oa.ba[1] = ba + 256; oa.ba[2] = ba + 512;
    oa.feat[0] = feat_w; oa.feat[1] = feat_t; oa.feat[2] = feat_d;
    oa.gamma[0] = ln_scale; oa.gamma[1] = ln_scale + 256; oa.gamma[2] = ln_scale + 512;
    oa.beta[0] = ln_bias; oa.beta[1] = ln_bias + 256; oa.beta[2] = ln_bias + 512;
    oa.op[0] = out; oa.op[1] = out + (size_t)NW * 256; oa.op[2] = out + (size_t)(NW + NT) * 256;
    oa.M[0] = NW; oa.M[1] = NT; oa.M[2] = ND;
    int bc = 0;
    for (int g = 0; g < 3; g++) { oa.bcum[g] = bc; bc += cdiv(oa.M[g], 64); }
    oa.bcum[3] = bc;
    oa.skipv = skip;
    out_all_ln<<<bc, b256, 0, stream>>>(oa);
  }

  (void)in_sizes; (void)n_in; (void)out_size; (void)ws_size;
}